// Round 1
// baseline (1340.883 us; speedup 1.0000x reference)
//
#include <hip/hip_runtime.h>
#include <hip/hip_bf16.h>

#define DEVINL static __device__ __forceinline__

DEVINL float siluf(float x) { return x * (1.0f / (1.0f + __expf(-x))); }

// ===================== precompute row-GEMMs =====================
// out[r,c] = bias[c] + sum_k in[r,k]*w[k,c]   (blockDim.x == C, one block per row)
__global__ void rowgemm_kernel(const float* __restrict__ in, const float* __restrict__ w,
                               const float* __restrict__ bias, float* __restrict__ out,
                               int K, int C) {
  __shared__ float srow[256];
  const int r = blockIdx.x;
  for (int k = threadIdx.x; k < K; k += blockDim.x) srow[k] = in[(size_t)r * K + k];
  __syncthreads();
  const int c = threadIdx.x;
  float acc = bias ? bias[c] : 0.0f;
  for (int k = 0; k < K; ++k) acc += srow[k] * w[(size_t)k * C + c];
  out[(size_t)r * C + c] = acc;
}

// ===================== main message kernel =====================
// grid = 4096 = 512 (b,q) x 8 k-tiles of 64 rows; block = 512 threads
__global__ __launch_bounds__(512) void msg_kernel(
    const float* __restrict__ equis, const float* __restrict__ cond_equis,
    const float* __restrict__ edges,
    const float* __restrict__ qm, const float* __restrict__ km,
    const float* __restrict__ w1, const float* __restrict__ b1,
    const float* __restrict__ w2, const float* __restrict__ b2,
    float* __restrict__ edge_out, __hip_bfloat16* __restrict__ scores) {
  __shared__ __align__(16) float feats[64][256];
  __shared__ __align__(16) float ht[64][256];
  __shared__ __align__(16) float wbuf[16 * 256];

  const int bq = blockIdx.x >> 3;   // 0..511 = b*256+q
  const int b  = bq >> 8;
  const int q  = bq & 255;
  const int k0 = (blockIdx.x & 7) * 64;
  const int tid = threadIdx.x;

  // ---- stage feats tile: cols [qmsg | kmsg | dot | edges] ----
  {
    const int c = tid & 255;
    const int rhalf = tid >> 8;     // 0/1
    float qv = 0.f, e0 = 0.f, e1 = 0.f, e2 = 0.f;
    if (c < 64) {
      qv = qm[bq * 64 + c];
    } else if (c >= 128 && c < 192) {
      const float* eq = equis + (size_t)(b * 256 + q) * 192 + (c - 128);
      e0 = eq[0]; e1 = eq[64]; e2 = eq[128];
    }
    for (int rr = 0; rr < 32; ++rr) {
      const int r = rhalf * 32 + rr;
      const int kg = k0 + r;
      float v;
      if (c < 64)        v = qv;
      else if (c < 128)  v = km[(b * 512 + kg) * 64 + (c - 64)];
      else if (c < 192) {
        const float* ce = cond_equis + (size_t)(b * 512 + kg) * 192 + (c - 128);
        v = e0 * ce[0] + e1 * ce[64] + e2 * ce[128];
      } else             v = edges[((size_t)bq * 512 + kg) * 64 + (c - 192)];
      feats[r][c] = v;
    }
  }

  // ---- GEMM1: ht = silu(feats @ w1 + b1), per-thread 8 rows x 4 cols ----
  {
    const int cg = tid & 63, rb = tid >> 6;
    const int c0 = cg * 4, r0 = rb * 8;
    float acc[8][4];
    const float4 b4 = *(const float4*)(b1 + c0);
    #pragma unroll
    for (int i = 0; i < 8; ++i) { acc[i][0]=b4.x; acc[i][1]=b4.y; acc[i][2]=b4.z; acc[i][3]=b4.w; }
    for (int kc = 0; kc < 16; ++kc) {
      __syncthreads();
      { // stage w1 rows [kc*16, kc*16+16) = 4096 floats
        const float4* src = (const float4*)(w1 + kc * 16 * 256);
        float4* dst = (float4*)wbuf;
        dst[tid] = src[tid];
        dst[tid + 512] = src[tid + 512];
      }
      __syncthreads();
      #pragma unroll
      for (int kk4 = 0; kk4 < 4; ++kk4) {
        const int kb = kk4 * 4;
        const float4 w0  = *(const float4*)(wbuf + (kb + 0) * 256 + c0);
        const float4 w1v = *(const float4*)(wbuf + (kb + 1) * 256 + c0);
        const float4 w2v = *(const float4*)(wbuf + (kb + 2) * 256 + c0);
        const float4 w3v = *(const float4*)(wbuf + (kb + 3) * 256 + c0);
        #pragma unroll
        for (int i = 0; i < 8; ++i) {
          const float4 f = *(const float4*)(&feats[r0 + i][kc * 16 + kb]);
          acc[i][0] += f.x * w0.x + f.y * w1v.x + f.z * w2v.x + f.w * w3v.x;
          acc[i][1] += f.x * w0.y + f.y * w1v.y + f.z * w2v.y + f.w * w3v.y;
          acc[i][2] += f.x * w0.z + f.y * w1v.z + f.z * w2v.z + f.w * w3v.z;
          acc[i][3] += f.x * w0.w + f.y * w1v.w + f.z * w2v.w + f.w * w3v.w;
        }
      }
    }
    #pragma unroll
    for (int i = 0; i < 8; ++i) {
      float4 h4;
      h4.x = siluf(acc[i][0]); h4.y = siluf(acc[i][1]);
      h4.z = siluf(acc[i][2]); h4.w = siluf(acc[i][3]);
      *(float4*)(&ht[r0 + i][c0]) = h4;
    }
  }

  // ---- GEMM2: messages = ht @ w2 + b2 ; 576 slots of 4 rows x 4 cols ----
  {
    const int slotA = tid;
    const int rA = (slotA / 36) * 4, cA = (slotA % 36) * 4;
    const bool hasB = (tid < 64);
    const int slotB = tid + 512;
    const int rB = (slotB / 36) * 4, cB = (slotB % 36) * 4;
    float accA[16], accB[16];
    {
      const float4 bA = *(const float4*)(b2 + cA);
      #pragma unroll
      for (int i = 0; i < 4; ++i) { accA[i*4+0]=bA.x; accA[i*4+1]=bA.y; accA[i*4+2]=bA.z; accA[i*4+3]=bA.w; }
      if (hasB) {
        const float4 bB = *(const float4*)(b2 + cB);
        #pragma unroll
        for (int i = 0; i < 4; ++i) { accB[i*4+0]=bB.x; accB[i*4+1]=bB.y; accB[i*4+2]=bB.z; accB[i*4+3]=bB.w; }
      }
    }
    for (int kc = 0; kc < 16; ++kc) {
      __syncthreads();
      { // stage w2 rows [kc*16, kc*16+16) = 2304 floats = 576 float4
        const float4* src = (const float4*)(w2 + kc * 16 * 144);
        float4* dst = (float4*)wbuf;
        for (int i = tid; i < 576; i += 512) dst[i] = src[i];
      }
      __syncthreads();
      #pragma unroll
      for (int kk4 = 0; kk4 < 4; ++kk4) {
        const int kb = kk4 * 4;
        {
          const float4 wa0 = *(const float4*)(wbuf + (kb + 0) * 144 + cA);
          const float4 wa1 = *(const float4*)(wbuf + (kb + 1) * 144 + cA);
          const float4 wa2 = *(const float4*)(wbuf + (kb + 2) * 144 + cA);
          const float4 wa3 = *(const float4*)(wbuf + (kb + 3) * 144 + cA);
          #pragma unroll
          for (int i = 0; i < 4; ++i) {
            const float4 f = *(const float4*)(&ht[rA + i][kc * 16 + kb]);
            accA[i*4+0] += f.x*wa0.x + f.y*wa1.x + f.z*wa2.x + f.w*wa3.x;
            accA[i*4+1] += f.x*wa0.y + f.y*wa1.y + f.z*wa2.y + f.w*wa3.y;
            accA[i*4+2] += f.x*wa0.z + f.y*wa1.z + f.z*wa2.z + f.w*wa3.z;
            accA[i*4+3] += f.x*wa0.w + f.y*wa1.w + f.z*wa2.w + f.w*wa3.w;
          }
        }
        if (hasB) {
          const float4 wb0 = *(const float4*)(wbuf + (kb + 0) * 144 + cB);
          const float4 wb1 = *(const float4*)(wbuf + (kb + 1) * 144 + cB);
          const float4 wb2 = *(const float4*)(wbuf + (kb + 2) * 144 + cB);
          const float4 wb3 = *(const float4*)(wbuf + (kb + 3) * 144 + cB);
          #pragma unroll
          for (int i = 0; i < 4; ++i) {
            const float4 f = *(const float4*)(&ht[rB + i][kc * 16 + kb]);
            accB[i*4+0] += f.x*wb0.x + f.y*wb1.x + f.z*wb2.x + f.w*wb3.x;
            accB[i*4+1] += f.x*wb0.y + f.y*wb1.y + f.z*wb2.y + f.w*wb3.y;
            accB[i*4+2] += f.x*wb0.z + f.y*wb1.z + f.z*wb2.z + f.w*wb3.z;
            accB[i*4+3] += f.x*wb0.w + f.y*wb1.w + f.z*wb2.w + f.w*wb3.w;
          }
        }
      }
    }
    // scatter: ch<80 -> scores (bf16), ch>=80 -> edge_out (fp32)
    #pragma unroll
    for (int i = 0; i < 4; ++i) {
      const int kg = k0 + rA + i;
      if (cA < 80) {
        __hip_bfloat16* sp = scores + ((size_t)bq * 512 + kg) * 80 + cA;
        sp[0] = __float2bfloat16(accA[i*4+0]); sp[1] = __float2bfloat16(accA[i*4+1]);
        sp[2] = __float2bfloat16(accA[i*4+2]); sp[3] = __float2bfloat16(accA[i*4+3]);
      } else {
        float4 v; v.x=accA[i*4+0]; v.y=accA[i*4+1]; v.z=accA[i*4+2]; v.w=accA[i*4+3];
        *(float4*)(edge_out + ((size_t)bq * 512 + kg) * 64 + (cA - 80)) = v;
      }
    }
    if (hasB) {
      #pragma unroll
      for (int i = 0; i < 4; ++i) {
        const int kg = k0 + rB + i;
        if (cB < 80) {
          __hip_bfloat16* sp = scores + ((size_t)bq * 512 + kg) * 80 + cB;
          sp[0] = __float2bfloat16(accB[i*4+0]); sp[1] = __float2bfloat16(accB[i*4+1]);
          sp[2] = __float2bfloat16(accB[i*4+2]); sp[3] = __float2bfloat16(accB[i*4+3]);
        } else {
          float4 v; v.x=accB[i*4+0]; v.y=accB[i*4+1]; v.z=accB[i*4+2]; v.w=accB[i*4+3];
          *(float4*)(edge_out + ((size_t)bq * 512 + kg) * 64 + (cB - 80)) = v;
        }
      }
    }
  }
}

// ===================== attention + outputs =====================
// one block (256 thr) per (b,q)
__global__ __launch_bounds__(256) void attn_kernel(
    const __hip_bfloat16* __restrict__ scores, const int* __restrict__ adj,
    const float* __restrict__ proj, const float* __restrict__ pf,
    const float* __restrict__ eow, const float* __restrict__ iow,
    const float* __restrict__ iob, float* __restrict__ out) {
  __shared__ int ams[512];
  __shared__ float redM[4][64];
  __shared__ float redA[4][5][64];
  __shared__ float eo_s[3][64];
  __shared__ float redBm[16][16];
  __shared__ float redBz[16][16];
  __shared__ float redBs[16][16];
  __shared__ __align__(16) float ioB[16][16][16];
  __shared__ float io_s[256];

  const int bq = blockIdx.x;        // b*256+q
  const int b = bq >> 8;
  const int tid = threadIdx.x;
  const __hip_bfloat16* sc = scores + (size_t)bq * 512 * 80;

  ams[tid]       = adj[(size_t)bq * 512 + tid];
  ams[tid + 256] = adj[(size_t)bq * 512 + tid + 256];
  __syncthreads();

  // ---- Phase A: equi attention over 64 channels; 4 k-groups of 128 ----
  {
    const int d = tid & 63, g = tid >> 6;
    const int ks = g * 128;
    float m = -1e30f;
    for (int k = ks; k < ks + 128; ++k)
      if (ams[k]) m = fmaxf(m, __bfloat162float(sc[k * 80 + d]));
    redM[g][d] = m;
    __syncthreads();
    m = fmaxf(fmaxf(redM[0][d], redM[1][d]), fmaxf(redM[2][d], redM[3][d]));
    float z = 0.f, s2 = 0.f, a0 = 0.f, a1 = 0.f, a2 = 0.f;
    for (int k = ks; k < ks + 128; ++k) {
      if (!ams[k]) continue;
      const float p = __expf(__bfloat162float(sc[k * 80 + d]) - m);
      z += p; s2 += p * p;
      const float* pr = proj + (size_t)(b * 512 + k) * 192 + d;
      a0 += p * pr[0]; a1 += p * pr[64]; a2 += p * pr[128];
    }
    redA[g][0][d] = z;  redA[g][1][d] = s2;
    redA[g][2][d] = a0; redA[g][3][d] = a1; redA[g][4][d] = a2;
    __syncthreads();
    float zt=0.f, s2t=0.f, e0t=0.f, e1t=0.f, e2t=0.f;
    #pragma unroll
    for (int gg = 0; gg < 4; ++gg) {
      zt  += redA[gg][0][d]; s2t += redA[gg][1][d];
      e0t += redA[gg][2][d]; e1t += redA[gg][3][d]; e2t += redA[gg][4][d];
    }
    const float inv = 1.f / zt;
    const float scale = sqrtf(s2t) * inv * inv;   // (1/z) * sqrt(s2)/z
    if (g < 3) eo_s[g][d] = ((g == 0) ? e0t : (g == 1) ? e1t : e2t) * scale;
  }
  __syncthreads();
  if (tid < 192) {   // equi_out = eo @ equi_out_w
    const int x = tid >> 6, e = tid & 63;
    float a = 0.f;
    for (int dd = 0; dd < 64; ++dd) a += eo_s[x][dd] * eow[dd * 64 + e];
    out[(size_t)(bq * 3 + x) * 64 + e] = a;
  }

  // ---- Phase B: inv attention, 16 heads x 16 dims; 16 k-groups of 32 ----
  {
    const int h = tid & 15, g = tid >> 4;
    const int ks = g * 32;
    float m = -1e30f;
    for (int k = ks; k < ks + 32; ++k)
      if (ams[k]) m = fmaxf(m, __bfloat162float(sc[k * 80 + 64 + h]));
    redBm[g][h] = m;
    __syncthreads();
    float mm = -1e30f;
    #pragma unroll
    for (int gg = 0; gg < 16; ++gg) mm = fmaxf(mm, redBm[gg][h]);
    float z = 0.f, s2 = 0.f;
    float io[16];
    #pragma unroll
    for (int dd = 0; dd < 16; ++dd) io[dd] = 0.f;
    for (int k = ks; k < ks + 32; ++k) {
      if (!ams[k]) continue;
      const float p = __expf(__bfloat162float(sc[k * 80 + 64 + h]) - mm);
      z += p; s2 += p * p;
      const float4* hp = (const float4*)(pf + (size_t)(b * 512 + k) * 256 + h * 16);
      const float4 v0 = hp[0], v1 = hp[1], v2 = hp[2], v3 = hp[3];
      io[0]+=p*v0.x;  io[1]+=p*v0.y;  io[2]+=p*v0.z;  io[3]+=p*v0.w;
      io[4]+=p*v1.x;  io[5]+=p*v1.y;  io[6]+=p*v1.z;  io[7]+=p*v1.w;
      io[8]+=p*v2.x;  io[9]+=p*v2.y;  io[10]+=p*v2.z; io[11]+=p*v2.w;
      io[12]+=p*v3.x; io[13]+=p*v3.y; io[14]+=p*v3.z; io[15]+=p*v3.w;
    }
    redBz[g][h] = z; redBs[g][h] = s2;
    #pragma unroll
    for (int dd = 0; dd < 16; ++dd) ioB[g][h][dd] = io[dd];
    __syncthreads();
    const int h2 = tid >> 4, dd = tid & 15;
    float zt = 0.f, s2t = 0.f, iot = 0.f;
    #pragma unroll
    for (int gg = 0; gg < 16; ++gg) {
      zt += redBz[gg][h2]; s2t += redBs[gg][h2]; iot += ioB[gg][h2][dd];
    }
    const float inv = 1.f / zt;
    io_s[h2 * 16 + dd] = iot * sqrtf(s2t) * inv * inv;
  }
  __syncthreads();
  {   // inv_out = io @ inv_out_w + iob
    float a = iob[tid];
    for (int k = 0; k < 256; ++k) a += io_s[k] * iow[k * 256 + tid];
    out[98304 + (size_t)bq * 256 + tid] = a;
  }
}

// ===================== launch =====================
extern "C" void kernel_launch(void* const* d_in, const int* in_sizes, int n_in,
                              void* d_out, int out_size, void* d_ws, size_t ws_size,
                              hipStream_t stream) {
  const float* equis      = (const float*)d_in[0];
  const float* invs       = (const float*)d_in[1];
  const float* cond_equis = (const float*)d_in[2];
  const float* cond_invs  = (const float*)d_in[3];
  const float* edges      = (const float*)d_in[4];
  const int*   adj        = (const int*)d_in[5];
  const float* q_w  = (const float*)d_in[6];
  const float* q_b  = (const float*)d_in[7];
  const float* k_w  = (const float*)d_in[8];
  const float* k_b  = (const float*)d_in[9];
  const float* w1   = (const float*)d_in[10];
  const float* b1   = (const float*)d_in[11];
  const float* w2   = (const float*)d_in[12];
  const float* b2   = (const float*)d_in[13];
  const float* equi_in_w  = (const float*)d_in[14];
  const float* equi_out_w = (const float*)d_in[15];
  const float* inv_in_w   = (const float*)d_in[16];
  const float* inv_in_b   = (const float*)d_in[17];
  const float* inv_out_w  = (const float*)d_in[18];
  const float* inv_out_b  = (const float*)d_in[19];

  float* out = (float*)d_out;
  float* ws  = (float*)d_ws;
  // ws layout (floats): qm[32768] km[65536] proj[196608] pf[262144] then bf16 scores
  float* qm   = ws;
  float* km   = ws + 32768;
  float* proj = ws + 98304;
  float* pf   = ws + 294912;
  __hip_bfloat16* scores = (__hip_bfloat16*)(ws + 557056);   // 512*512*80 bf16 = 41.9 MB

  rowgemm_kernel<<<512,  64,  0, stream>>>(invs,       q_w,       q_b,       qm,   256, 64);
  rowgemm_kernel<<<1024, 64,  0, stream>>>(cond_invs,  k_w,       k_b,       km,   256, 64);
  rowgemm_kernel<<<3072, 64,  0, stream>>>(cond_equis, equi_in_w, nullptr,   proj, 64,  64);
  rowgemm_kernel<<<1024, 256, 0, stream>>>(cond_invs,  inv_in_w,  inv_in_b,  pf,   256, 256);

  msg_kernel<<<4096, 512, 0, stream>>>(equis, cond_equis, edges, qm, km,
                                       w1, b1, w2, b2,
                                       out + 229376 /*edge_out*/, scores);

  attn_kernel<<<512, 256, 0, stream>>>(scores, adj, proj, pf,
                                       equi_out_w, inv_out_w, inv_out_b, out);
}

// Round 2
// 421.667 us; speedup vs baseline: 3.1800x; 3.1800x over previous
//
#include <hip/hip_runtime.h>
#include <hip/hip_bf16.h>

#define DEVINL static __device__ __forceinline__

typedef __attribute__((ext_vector_type(8))) short bf16x8;
typedef __attribute__((ext_vector_type(4))) float f32x4;
typedef __attribute__((ext_vector_type(4))) unsigned short us4;

DEVINL float siluf(float x) { return x / (1.0f + __expf(-x)); }
DEVINL unsigned short bfb(float x) { __hip_bfloat16 h = __float2bfloat16(x); return *(unsigned short*)&h; }

// ===================== prep: transpose weights to bf16 k-major =====================
// wt[c][k] = bf16(w[k][c]); K=256 fixed, grid.x = C
__global__ void transpose_w_kernel(const float* __restrict__ w, unsigned short* __restrict__ wt, int C) {
  const int c = blockIdx.x, k = threadIdx.x;
  wt[(size_t)c * 256 + k] = bfb(w[(size_t)k * C + c]);
}

// ===================== precompute row-GEMMs (fp32, tiny) =====================
__global__ void rowgemm_kernel(const float* __restrict__ in, const float* __restrict__ w,
                               const float* __restrict__ bias, float* __restrict__ out,
                               int K, int C) {
  __shared__ float srow[256];
  const int r = blockIdx.x;
  for (int k = threadIdx.x; k < K; k += blockDim.x) srow[k] = in[(size_t)r * K + k];
  __syncthreads();
  const int c = threadIdx.x;
  float acc = bias ? bias[c] : 0.0f;
  for (int k = 0; k < K; ++k) acc += srow[k] * w[(size_t)k * C + c];
  out[(size_t)r * C + c] = acc;
}

// ===================== GEMM2 + store (templated for static unroll) =====================
template <int NCT, int CB>
DEVINL void gemm2_store(const unsigned short (*tile)[264],
                        const unsigned short* __restrict__ w2t, const float* __restrict__ b2,
                        float* __restrict__ edge_out, __hip_bfloat16* __restrict__ sct,
                        int bq, int k0, int wm, int lj, int lkb, int lr4) {
  f32x4 acc[NCT][4];
  #pragma unroll
  for (int ct = 0; ct < NCT; ++ct) {
    const float4 bb = *(const float4*)&b2[CB + ct * 16 + lr4];
    #pragma unroll
    for (int rt = 0; rt < 4; ++rt) { acc[ct][rt][0] = bb.x; acc[ct][rt][1] = bb.y; acc[ct][rt][2] = bb.z; acc[ct][rt][3] = bb.w; }
  }
  #pragma unroll 2
  for (int kk = 0; kk < 8; ++kk) {
    bf16x8 fb[4], wa[NCT];
    #pragma unroll
    for (int rt = 0; rt < 4; ++rt)
      fb[rt] = *(const bf16x8*)&tile[wm * 64 + rt * 16 + lj][kk * 32 + lkb];
    #pragma unroll
    for (int ct = 0; ct < NCT; ++ct)
      wa[ct] = *(const bf16x8*)&w2t[(size_t)(CB + ct * 16 + lj) * 256 + kk * 32 + lkb];
    #pragma unroll
    for (int ct = 0; ct < NCT; ++ct)
      #pragma unroll
      for (int rt = 0; rt < 4; ++rt)
        acc[ct][rt] = __builtin_amdgcn_mfma_f32_16x16x32_bf16(wa[ct], fb[rt], acc[ct][rt], 0, 0, 0);
  }
  if (CB == 0) {
    // score channels 0..79 -> sct[bq][ch][k] bf16
    #pragma unroll
    for (int ct = 0; ct < NCT; ++ct)
      #pragma unroll
      for (int rt = 0; rt < 4; ++rt) {
        const int kgl = k0 + wm * 64 + rt * 16 + lj;
        __hip_bfloat16* sp = sct + ((size_t)bq * 80 + ct * 16 + lr4) * 512 + kgl;
        #pragma unroll
        for (int rr = 0; rr < 4; ++rr) sp[rr * 512] = __float2bfloat16(acc[ct][rt][rr]);
      }
  } else {
    // edge channels (c-80) in 0..63 -> edge_out[bq][k][64] fp32, float4 stores
    #pragma unroll
    for (int ct = 0; ct < NCT; ++ct)
      #pragma unroll
      for (int rt = 0; rt < 4; ++rt) {
        const int kgl = k0 + wm * 64 + rt * 16 + lj;
        float4 v; v.x = acc[ct][rt][0]; v.y = acc[ct][rt][1]; v.z = acc[ct][rt][2]; v.w = acc[ct][rt][3];
        *(float4*)&edge_out[((size_t)bq * 512 + kgl) * 64 + ct * 16 + lr4] = v;
      }
  }
}

// ===================== main message kernel (MFMA) =====================
// grid = 512 (b,q) x 4 k-tiles of 128 rows; block = 256 threads (4 waves, 2M x 2N)
__global__ __launch_bounds__(256) void msg_kernel(
    const float* __restrict__ equis, const float* __restrict__ cond_equis,
    const float* __restrict__ edges,
    const float* __restrict__ qm, const float* __restrict__ km,
    const unsigned short* __restrict__ w1t, const float* __restrict__ b1,
    const unsigned short* __restrict__ w2t, const float* __restrict__ b2,
    float* __restrict__ edge_out, __hip_bfloat16* __restrict__ sct) {
  __shared__ __align__(16) unsigned short tile[128][264];   // feats, then h (reused)
  __shared__ __align__(16) float eq_s[192];
  __shared__ __align__(16) float qm_s[64];

  const int bq = blockIdx.x >> 2;     // b*256+q
  const int b  = bq >> 8;
  const int q  = bq & 255;
  const int k0 = (blockIdx.x & 3) * 128;
  const int tid = threadIdx.x;

  if (tid < 192) eq_s[tid] = equis[(size_t)(b * 256 + q) * 192 + tid];
  else           qm_s[tid - 192] = qm[(size_t)bq * 64 + (tid - 192)];
  __syncthreads();

  // ---- build feats tile in bf16: cols [qmsg | kmsg | dot | edges] ----
  {
    const int r = tid & 127, half = tid >> 7;   // wave-uniform half
    const int kg = k0 + r;
    const float* kmr = km + (size_t)(b * 512 + kg) * 64;
    const float* cer = cond_equis + (size_t)(b * 512 + kg) * 192;
    const float* edr = edges + ((size_t)bq * 512 + kg) * 64;
    #pragma unroll
    for (int j = 0; j < 32; ++j) {
      const int c = half * 128 + j * 4;
      float4 v;
      if (c < 64)        v = *(const float4*)&qm_s[c];
      else if (c < 128)  v = *(const float4*)&kmr[c - 64];
      else if (c < 192) {
        const int d = c - 128;
        const float4 c0 = *(const float4*)&cer[d];
        const float4 c1 = *(const float4*)&cer[64 + d];
        const float4 c2 = *(const float4*)&cer[128 + d];
        const float4 e0 = *(const float4*)&eq_s[d];
        const float4 e1 = *(const float4*)&eq_s[64 + d];
        const float4 e2 = *(const float4*)&eq_s[128 + d];
        v.x = e0.x * c0.x + e1.x * c1.x + e2.x * c2.x;
        v.y = e0.y * c0.y + e1.y * c1.y + e2.y * c2.y;
        v.z = e0.z * c0.z + e1.z * c1.z + e2.z * c2.z;
        v.w = e0.w * c0.w + e1.w * c1.w + e2.w * c2.w;
      } else             v = *(const float4*)&edr[c - 192];
      us4 u = { bfb(v.x), bfb(v.y), bfb(v.z), bfb(v.w) };
      *(us4*)&tile[r][c] = u;
    }
  }
  __syncthreads();

  const int lane = tid & 63;
  const int wv = tid >> 6, wm = wv >> 1, wn = wv & 1;
  const int lj  = lane & 15;          // j index (row r of output)
  const int lkb = (lane >> 4) * 8;    // k base offset
  const int lr4 = (lane >> 4) * 4;    // output channel group offset

  // ---- GEMM1 (transposed): D1[c][r] = w1t . feats, c in [wn*128, +128), r in [wm*64, +64) ----
  f32x4 acc[8][4];
  #pragma unroll
  for (int ct = 0; ct < 8; ++ct) {
    const float4 bb = *(const float4*)&b1[wn * 128 + ct * 16 + lr4];
    #pragma unroll
    for (int rt = 0; rt < 4; ++rt) { acc[ct][rt][0] = bb.x; acc[ct][rt][1] = bb.y; acc[ct][rt][2] = bb.z; acc[ct][rt][3] = bb.w; }
  }
  #pragma unroll 2
  for (int kk = 0; kk < 8; ++kk) {
    bf16x8 fb[4], wa[8];
    #pragma unroll
    for (int rt = 0; rt < 4; ++rt)
      fb[rt] = *(const bf16x8*)&tile[wm * 64 + rt * 16 + lj][kk * 32 + lkb];
    #pragma unroll
    for (int ct = 0; ct < 8; ++ct)
      wa[ct] = *(const bf16x8*)&w1t[(size_t)(wn * 128 + ct * 16 + lj) * 256 + kk * 32 + lkb];
    #pragma unroll
    for (int ct = 0; ct < 8; ++ct)
      #pragma unroll
      for (int rt = 0; rt < 4; ++rt)
        acc[ct][rt] = __builtin_amdgcn_mfma_f32_16x16x32_bf16(wa[ct], fb[rt], acc[ct][rt], 0, 0, 0);
  }
  __syncthreads();   // everyone done reading feats

  // ---- h = silu(acc) -> bf16 back into tile (packed b64 writes) ----
  #pragma unroll
  for (int ct = 0; ct < 8; ++ct)
    #pragma unroll
    for (int rt = 0; rt < 4; ++rt) {
      us4 u = { bfb(siluf(acc[ct][rt][0])), bfb(siluf(acc[ct][rt][1])),
                bfb(siluf(acc[ct][rt][2])), bfb(siluf(acc[ct][rt][3])) };
      *(us4*)&tile[wm * 64 + rt * 16 + lj][wn * 128 + ct * 16 + lr4] = u;
    }
  __syncthreads();

  // ---- GEMM2 (transposed) + scatter ----
  if (wn == 0) gemm2_store<5, 0 >(tile, w2t, b2, edge_out, sct, bq, k0, wm, lj, lkb, lr4);
  else         gemm2_store<4, 80>(tile, w2t, b2, edge_out, sct, bq, k0, wm, lj, lkb, lr4);
}

// ===================== attention + outputs =====================
// one block (256 thr) per (b,q); scores are channel-major sct[bq][80][512]
__global__ __launch_bounds__(256) void attn_kernel(
    const __hip_bfloat16* __restrict__ sct, const int* __restrict__ adj,
    const float* __restrict__ proj, const float* __restrict__ pf,
    const float* __restrict__ eow, const float* __restrict__ iow,
    const float* __restrict__ iob, float* __restrict__ out) {
  __shared__ int ams[512];
  __shared__ float redM[4][64];
  __shared__ float redA[4][5][64];
  __shared__ float eo_s[3][64];
  __shared__ float redBm[16][16];
  __shared__ float redBz[16][16];
  __shared__ float redBs[16][16];
  __shared__ __align__(16) float ioB[16][16][16];
  __shared__ float io_s[256];

  const int bq = blockIdx.x;        // b*256+q
  const int b = bq >> 8;
  const int tid = threadIdx.x;

  ams[tid]       = adj[(size_t)bq * 512 + tid];
  ams[tid + 256] = adj[(size_t)bq * 512 + tid + 256];
  __syncthreads();

  // ---- Phase A: equi attention over 64 channels; 4 k-groups of 128 ----
  {
    const int d = tid & 63, g = tid >> 6;
    const int ks = g * 128;
    const __hip_bfloat16* sA = sct + ((size_t)bq * 80 + d) * 512;
    float m = -1e30f;
    for (int k = ks; k < ks + 128; ++k)
      if (ams[k]) m = fmaxf(m, __bfloat162float(sA[k]));
    redM[g][d] = m;
    __syncthreads();
    m = fmaxf(fmaxf(redM[0][d], redM[1][d]), fmaxf(redM[2][d], redM[3][d]));
    float z = 0.f, s2 = 0.f, a0 = 0.f, a1 = 0.f, a2 = 0.f;
    for (int k = ks; k < ks + 128; ++k) {
      if (!ams[k]) continue;
      const float p = __expf(__bfloat162float(sA[k]) - m);
      z += p; s2 += p * p;
      const float* pr = proj + (size_t)(b * 512 + k) * 192 + d;
      a0 += p * pr[0]; a1 += p * pr[64]; a2 += p * pr[128];
    }
    redA[g][0][d] = z;  redA[g][1][d] = s2;
    redA[g][2][d] = a0; redA[g][3][d] = a1; redA[g][4][d] = a2;
    __syncthreads();
    float zt = 0.f, s2t = 0.f, e0t = 0.f, e1t = 0.f, e2t = 0.f;
    #pragma unroll
    for (int gg = 0; gg < 4; ++gg) {
      zt  += redA[gg][0][d]; s2t += redA[gg][1][d];
      e0t += redA[gg][2][d]; e1t += redA[gg][3][d]; e2t += redA[gg][4][d];
    }
    const float inv = 1.f / zt;
    const float scale = sqrtf(s2t) * inv * inv;
    if (g < 3) eo_s[g][d] = ((g == 0) ? e0t : (g == 1) ? e1t : e2t) * scale;
  }
  __syncthreads();
  if (tid < 192) {   // equi_out = eo @ equi_out_w
    const int x = tid >> 6, e = tid & 63;
    float a = 0.f;
    for (int dd = 0; dd < 64; ++dd) a += eo_s[x][dd] * eow[dd * 64 + e];
    out[(size_t)(bq * 3 + x) * 64 + e] = a;
  }

  // ---- Phase B: inv attention, 16 heads x 16 dims; 16 k-groups of 32 ----
  {
    const int h = tid & 15, g = tid >> 4;
    const int ks = g * 32;
    const __hip_bfloat16* sB = sct + ((size_t)bq * 80 + 64 + h) * 512;
    float m = -1e30f;
    for (int k = ks; k < ks + 32; ++k)
      if (ams[k]) m = fmaxf(m, __bfloat162float(sB[k]));
    redBm[g][h] = m;
    __syncthreads();
    float mm = -1e30f;
    #pragma unroll
    for (int gg = 0; gg < 16; ++gg) mm = fmaxf(mm, redBm[gg][h]);
    float z = 0.f, s2 = 0.f;
    float io[16];
    #pragma unroll
    for (int dd = 0; dd < 16; ++dd) io[dd] = 0.f;
    for (int k = ks; k < ks + 32; ++k) {
      if (!ams[k]) continue;
      const float p = __expf(__bfloat162float(sB[k]) - mm);
      z += p; s2 += p * p;
      const float4* hp = (const float4*)(pf + (size_t)(b * 512 + k) * 256 + h * 16);
      const float4 v0 = hp[0], v1 = hp[1], v2 = hp[2], v3 = hp[3];
      io[0]+=p*v0.x;  io[1]+=p*v0.y;  io[2]+=p*v0.z;  io[3]+=p*v0.w;
      io[4]+=p*v1.x;  io[5]+=p*v1.y;  io[6]+=p*v1.z;  io[7]+=p*v1.w;
      io[8]+=p*v2.x;  io[9]+=p*v2.y;  io[10]+=p*v2.z; io[11]+=p*v2.w;
      io[12]+=p*v3.x; io[13]+=p*v3.y; io[14]+=p*v3.z; io[15]+=p*v3.w;
    }
    redBz[g][h] = z; redBs[g][h] = s2;
    #pragma unroll
    for (int dd = 0; dd < 16; ++dd) ioB[g][h][dd] = io[dd];
    __syncthreads();
    const int h2 = tid >> 4, dd = tid & 15;
    float zt = 0.f, s2t = 0.f, iot = 0.f;
    #pragma unroll
    for (int gg = 0; gg < 16; ++gg) {
      zt += redBz[gg][h2]; s2t += redBs[gg][h2]; iot += ioB[gg][h2][dd];
    }
    const float inv = 1.f / zt;
    io_s[h2 * 16 + dd] = iot * sqrtf(s2t) * inv * inv;
  }
  __syncthreads();
  {   // inv_out = io @ inv_out_w + iob
    float a = iob[tid];
    for (int k = 0; k < 256; ++k) a += io_s[k] * iow[k * 256 + tid];
    out[98304 + (size_t)bq * 256 + tid] = a;
  }
}

// ===================== launch =====================
extern "C" void kernel_launch(void* const* d_in, const int* in_sizes, int n_in,
                              void* d_out, int out_size, void* d_ws, size_t ws_size,
                              hipStream_t stream) {
  const float* equis      = (const float*)d_in[0];
  const float* invs       = (const float*)d_in[1];
  const float* cond_equis = (const float*)d_in[2];
  const float* cond_invs  = (const float*)d_in[3];
  const float* edges      = (const float*)d_in[4];
  const int*   adj        = (const int*)d_in[5];
  const float* q_w  = (const float*)d_in[6];
  const float* q_b  = (const float*)d_in[7];
  const float* k_w  = (const float*)d_in[8];
  const float* k_b  = (const float*)d_in[9];
  const float* w1   = (const float*)d_in[10];
  const float* b1   = (const float*)d_in[11];
  const float* w2   = (const float*)d_in[12];
  const float* b2   = (const float*)d_in[13];
  const float* equi_in_w  = (const float*)d_in[14];
  const float* equi_out_w = (const float*)d_in[15];
  const float* inv_in_w   = (const float*)d_in[16];
  const float* inv_in_b   = (const float*)d_in[17];
  const float* inv_out_w  = (const float*)d_in[18];
  const float* inv_out_b  = (const float*)d_in[19];

  float* out = (float*)d_out;
  float* ws  = (float*)d_ws;
  // ws layout: [w1t bf16 65536][w2t bf16 36864] = 51200 floats, then fp32 tensors, then sct bf16
  unsigned short* w1t = (unsigned short*)ws;
  unsigned short* w2t = w1t + 65536;
  float* qm   = ws + 51200;
  float* km   = qm + 32768;
  float* proj = km + 65536;
  float* pf   = proj + 196608;
  __hip_bfloat16* sct = (__hip_bfloat16*)(pf + 262144);   // 512*80*512 bf16 = 41.9 MB

  transpose_w_kernel<<<256, 256, 0, stream>>>(w1, w1t, 256);
  transpose_w_kernel<<<144, 256, 0, stream>>>(w2, w2t, 144);
  rowgemm_kernel<<<512,  64,  0, stream>>>(invs,       q_w,       q_b,       qm,   256, 64);
  rowgemm_kernel<<<1024, 64,  0, stream>>>(cond_invs,  k_w,       k_b,       km,   256, 64);
  rowgemm_kernel<<<3072, 64,  0, stream>>>(cond_equis, equi_in_w, nullptr,   proj, 64,  64);
  rowgemm_kernel<<<1024, 256, 0, stream>>>(cond_invs,  inv_in_w,  inv_in_b,  pf,   256, 256);

  msg_kernel<<<2048, 256, 0, stream>>>(equis, cond_equis, edges, qm, km,
                                       w1t, b1, w2t, b2,
                                       out + 229376 /*edge_out*/, sct);

  attn_kernel<<<512, 256, 0, stream>>>(sct, adj, proj, pf,
                                       equi_out_w, inv_out_w, inv_out_b, out);
}

// Round 3
// 320.680 us; speedup vs baseline: 4.1814x; 1.3149x over previous
//
#include <hip/hip_runtime.h>
#include <hip/hip_bf16.h>

#define DEVINL static __device__ __forceinline__

typedef __attribute__((ext_vector_type(8))) short bf16x8;
typedef __attribute__((ext_vector_type(4))) float f32x4;
typedef __attribute__((ext_vector_type(4))) unsigned short us4;

DEVINL float siluf(float x) { return x / (1.0f + __expf(-x)); }
DEVINL unsigned short bfb(float x) { __hip_bfloat16 h = __float2bfloat16(x); return *(unsigned short*)&h; }

// ===================== prep: transpose weights to bf16 k-major =====================
__global__ void transpose_w_kernel(const float* __restrict__ w, unsigned short* __restrict__ wt, int C) {
  const int c = blockIdx.x, k = threadIdx.x;
  wt[(size_t)c * 256 + k] = bfb(w[(size_t)k * C + c]);
}

// ===================== precompute row-GEMMs (fp32, tiny) =====================
__global__ void rowgemm_kernel(const float* __restrict__ in, const float* __restrict__ w,
                               const float* __restrict__ bias, float* __restrict__ out,
                               int K, int C) {
  __shared__ float srow[256];
  const int r = blockIdx.x;
  for (int k = threadIdx.x; k < K; k += blockDim.x) srow[k] = in[(size_t)r * K + k];
  __syncthreads();
  const int c = threadIdx.x;
  float acc = bias ? bias[c] : 0.0f;
  for (int k = 0; k < K; ++k) acc += srow[k] * w[(size_t)k * C + c];
  out[(size_t)r * C + c] = acc;
}

// ===================== main message kernel (MFMA, 8 waves) =====================
// grid = 512 (b,q) x 4 k-tiles of 128 rows; block = 512 threads (8 waves: 2M x 4N)
__global__ __launch_bounds__(512, 4) void msg_kernel(
    const float* __restrict__ equis, const float* __restrict__ cond_equis,
    const float* __restrict__ edges,
    const float* __restrict__ qm, const float* __restrict__ km,
    const unsigned short* __restrict__ w1t, const float* __restrict__ b1,
    const unsigned short* __restrict__ w2t, const float* __restrict__ b2,
    float* __restrict__ edge_out, __hip_bfloat16* __restrict__ sct) {
  __shared__ __align__(16) unsigned short tile[128][264];   // feats, then h (reused)
  __shared__ __align__(16) float eq_s[192];
  __shared__ __align__(16) float qm_s[64];

  const int bq = blockIdx.x >> 2;     // b*256+q
  const int b  = bq >> 8;
  const int q  = bq & 255;
  const int k0 = (blockIdx.x & 3) * 128;
  const int tid = threadIdx.x;

  if (tid < 192) eq_s[tid] = equis[(size_t)(b * 256 + q) * 192 + tid];
  else if (tid < 256) qm_s[tid - 192] = qm[(size_t)bq * 64 + (tid - 192)];
  __syncthreads();

  // ---- build feats tile in bf16: cols [qmsg | kmsg | dot | edges] ----
  // 512 threads: r = tid&127, column-quarter cq = tid>>7 (wave-uniform)
  {
    const int r = tid & 127, cq = tid >> 7;
    const int kg = k0 + r;
    if (cq == 0) {
      #pragma unroll
      for (int j = 0; j < 16; ++j) {
        const float4 v = *(const float4*)&qm_s[j * 4];
        us4 u = { bfb(v.x), bfb(v.y), bfb(v.z), bfb(v.w) };
        *(us4*)&tile[r][j * 4] = u;
      }
    } else if (cq == 1) {
      const float* kmr = km + (size_t)(b * 512 + kg) * 64;
      #pragma unroll
      for (int j = 0; j < 16; ++j) {
        const float4 v = *(const float4*)&kmr[j * 4];
        us4 u = { bfb(v.x), bfb(v.y), bfb(v.z), bfb(v.w) };
        *(us4*)&tile[r][64 + j * 4] = u;
      }
    } else if (cq == 2) {
      const float* cer = cond_equis + (size_t)(b * 512 + kg) * 192;
      #pragma unroll
      for (int j = 0; j < 16; ++j) {
        const int d = j * 4;
        const float4 c0 = *(const float4*)&cer[d];
        const float4 c1 = *(const float4*)&cer[64 + d];
        const float4 c2 = *(const float4*)&cer[128 + d];
        const float4 e0 = *(const float4*)&eq_s[d];
        const float4 e1 = *(const float4*)&eq_s[64 + d];
        const float4 e2 = *(const float4*)&eq_s[128 + d];
        float4 v;
        v.x = e0.x * c0.x + e1.x * c1.x + e2.x * c2.x;
        v.y = e0.y * c0.y + e1.y * c1.y + e2.y * c2.y;
        v.z = e0.z * c0.z + e1.z * c1.z + e2.z * c2.z;
        v.w = e0.w * c0.w + e1.w * c1.w + e2.w * c2.w;
        us4 u = { bfb(v.x), bfb(v.y), bfb(v.z), bfb(v.w) };
        *(us4*)&tile[r][128 + d] = u;
      }
    } else {
      const float* edr = edges + ((size_t)bq * 512 + kg) * 64;
      #pragma unroll
      for (int j = 0; j < 16; ++j) {
        const float4 v = *(const float4*)&edr[j * 4];
        us4 u = { bfb(v.x), bfb(v.y), bfb(v.z), bfb(v.w) };
        *(us4*)&tile[r][192 + j * 4] = u;
      }
    }
  }
  __syncthreads();

  const int lane = tid & 63;
  const int wv = tid >> 6;
  const int wm = wv >> 2, wn = wv & 3;      // 2 row-halves x 4 channel-quarters
  const int lj  = lane & 15;                // output row index within 16
  const int lkb = (lane >> 4) * 8;          // k base offset
  const int lr4 = (lane >> 4) * 4;          // output channel sub-offset

  // ---- GEMM1 (transposed): D1[c][r], c in [wn*64,+64), r in [wm*64,+64) ----
  f32x4 acc[4][4];
  #pragma unroll
  for (int ct = 0; ct < 4; ++ct) {
    const float4 bb = *(const float4*)&b1[wn * 64 + ct * 16 + lr4];
    #pragma unroll
    for (int rt = 0; rt < 4; ++rt) { acc[ct][rt][0] = bb.x; acc[ct][rt][1] = bb.y; acc[ct][rt][2] = bb.z; acc[ct][rt][3] = bb.w; }
  }
  #pragma unroll 2
  for (int kk = 0; kk < 8; ++kk) {
    bf16x8 fb[4], wa[4];
    #pragma unroll
    for (int rt = 0; rt < 4; ++rt)
      fb[rt] = *(const bf16x8*)&tile[wm * 64 + rt * 16 + lj][kk * 32 + lkb];
    #pragma unroll
    for (int ct = 0; ct < 4; ++ct)
      wa[ct] = *(const bf16x8*)&w1t[(size_t)(wn * 64 + ct * 16 + lj) * 256 + kk * 32 + lkb];
    #pragma unroll
    for (int ct = 0; ct < 4; ++ct)
      #pragma unroll
      for (int rt = 0; rt < 4; ++rt)
        acc[ct][rt] = __builtin_amdgcn_mfma_f32_16x16x32_bf16(wa[ct], fb[rt], acc[ct][rt], 0, 0, 0);
  }
  __syncthreads();   // everyone done reading feats

  // ---- h = silu(acc) -> bf16 back into tile ----
  #pragma unroll
  for (int ct = 0; ct < 4; ++ct)
    #pragma unroll
    for (int rt = 0; rt < 4; ++rt) {
      us4 u = { bfb(siluf(acc[ct][rt][0])), bfb(siluf(acc[ct][rt][1])),
                bfb(siluf(acc[ct][rt][2])), bfb(siluf(acc[ct][rt][3])) };
      *(us4*)&tile[wm * 64 + rt * 16 + lj][wn * 64 + ct * 16 + lr4] = u;
    }
  __syncthreads();

  // ---- GEMM2 (transposed): 9 channel-tiles distributed t = it*4 + wn ----
  {
    f32x4 a2[3][4];
    #pragma unroll
    for (int it = 0; it < 3; ++it) {
      const int t = it * 4 + wn;
      if (t < 9) {
        const float4 bb = *(const float4*)&b2[t * 16 + lr4];
        #pragma unroll
        for (int rt = 0; rt < 4; ++rt) { a2[it][rt][0] = bb.x; a2[it][rt][1] = bb.y; a2[it][rt][2] = bb.z; a2[it][rt][3] = bb.w; }
      }
    }
    #pragma unroll 2
    for (int kk = 0; kk < 8; ++kk) {
      bf16x8 fb[4];
      #pragma unroll
      for (int rt = 0; rt < 4; ++rt)
        fb[rt] = *(const bf16x8*)&tile[wm * 64 + rt * 16 + lj][kk * 32 + lkb];
      #pragma unroll
      for (int it = 0; it < 3; ++it) {
        const int t = it * 4 + wn;
        if (t < 9) {
          const bf16x8 wa = *(const bf16x8*)&w2t[(size_t)(t * 16 + lj) * 256 + kk * 32 + lkb];
          #pragma unroll
          for (int rt = 0; rt < 4; ++rt)
            a2[it][rt] = __builtin_amdgcn_mfma_f32_16x16x32_bf16(wa, fb[rt], a2[it][rt], 0, 0, 0);
        }
      }
    }
    #pragma unroll
    for (int it = 0; it < 3; ++it) {
      const int t = it * 4 + wn;
      if (t < 9) {
        if (t < 5) {
          // score channels t*16+lr4 (+0..3) -> sct[bq][ch][k] bf16
          #pragma unroll
          for (int rt = 0; rt < 4; ++rt) {
            const int kgl = k0 + wm * 64 + rt * 16 + lj;
            __hip_bfloat16* sp = sct + ((size_t)bq * 80 + t * 16 + lr4) * 512 + kgl;
            #pragma unroll
            for (int rr = 0; rr < 4; ++rr) sp[rr * 512] = __float2bfloat16(a2[it][rt][rr]);
          }
        } else {
          // edge channels (t*16-80 + lr4) -> edge_out[bq][k][64] fp32
          #pragma unroll
          for (int rt = 0; rt < 4; ++rt) {
            const int kgl = k0 + wm * 64 + rt * 16 + lj;
            float4 v; v.x = a2[it][rt][0]; v.y = a2[it][rt][1]; v.z = a2[it][rt][2]; v.w = a2[it][rt][3];
            *(float4*)&edge_out[((size_t)bq * 512 + kgl) * 64 + (t * 16 - 80) + lr4] = v;
          }
        }
      }
    }
  }
}

// ===================== attention + outputs =====================
__global__ __launch_bounds__(256) void attn_kernel(
    const __hip_bfloat16* __restrict__ sct, const int* __restrict__ adj,
    const float* __restrict__ proj, const float* __restrict__ pf,
    const float* __restrict__ eow, const float* __restrict__ iow,
    const float* __restrict__ iob, float* __restrict__ out) {
  __shared__ int ams[512];
  __shared__ float redM[4][64];
  __shared__ float redA[4][5][64];
  __shared__ float eo_s[3][64];
  __shared__ float redBm[16][16];
  __shared__ float redBz[16][16];
  __shared__ float redBs[16][16];
  __shared__ __align__(16) float ioB[16][16][16];
  __shared__ float io_s[256];

  const int bq = blockIdx.x;        // b*256+q
  const int b = bq >> 8;
  const int tid = threadIdx.x;

  ams[tid]       = adj[(size_t)bq * 512 + tid];
  ams[tid + 256] = adj[(size_t)bq * 512 + tid + 256];
  __syncthreads();

  // ---- Phase A: equi attention over 64 channels; 4 k-groups of 128 ----
  {
    const int d = tid & 63, g = tid >> 6;
    const int ks = g * 128;
    const __hip_bfloat16* sA = sct + ((size_t)bq * 80 + d) * 512;
    float m = -1e30f;
    for (int k = ks; k < ks + 128; ++k)
      if (ams[k]) m = fmaxf(m, __bfloat162float(sA[k]));
    redM[g][d] = m;
    __syncthreads();
    m = fmaxf(fmaxf(redM[0][d], redM[1][d]), fmaxf(redM[2][d], redM[3][d]));
    float z = 0.f, s2 = 0.f, a0 = 0.f, a1 = 0.f, a2 = 0.f;
    for (int k = ks; k < ks + 128; ++k) {
      if (!ams[k]) continue;
      const float p = __expf(__bfloat162float(sA[k]) - m);
      z += p; s2 += p * p;
      const float* pr = proj + (size_t)(b * 512 + k) * 192 + d;
      a0 += p * pr[0]; a1 += p * pr[64]; a2 += p * pr[128];
    }
    redA[g][0][d] = z;  redA[g][1][d] = s2;
    redA[g][2][d] = a0; redA[g][3][d] = a1; redA[g][4][d] = a2;
    __syncthreads();
    float zt = 0.f, s2t = 0.f, e0t = 0.f, e1t = 0.f, e2t = 0.f;
    #pragma unroll
    for (int gg = 0; gg < 4; ++gg) {
      zt  += redA[gg][0][d]; s2t += redA[gg][1][d];
      e0t += redA[gg][2][d]; e1t += redA[gg][3][d]; e2t += redA[gg][4][d];
    }
    const float inv = 1.f / zt;
    const float scale = sqrtf(s2t) * inv * inv;
    if (g < 3) eo_s[g][d] = ((g == 0) ? e0t : (g == 1) ? e1t : e2t) * scale;
  }
  __syncthreads();
  if (tid < 192) {   // equi_out = eo @ equi_out_w
    const int x = tid >> 6, e = tid & 63;
    float a = 0.f;
    for (int dd = 0; dd < 64; ++dd) a += eo_s[x][dd] * eow[dd * 64 + e];
    out[(size_t)(bq * 3 + x) * 64 + e] = a;
  }

  // ---- Phase B: inv attention, 16 heads x 16 dims; 16 k-groups of 32 ----
  {
    const int h = tid & 15, g = tid >> 4;
    const int ks = g * 32;
    const __hip_bfloat16* sB = sct + ((size_t)bq * 80 + 64 + h) * 512;
    float m = -1e30f;
    for (int k = ks; k < ks + 32; ++k)
      if (ams[k]) m = fmaxf(m, __bfloat162float(sB[k]));
    redBm[g][h] = m;
    __syncthreads();
    float mm = -1e30f;
    #pragma unroll
    for (int gg = 0; gg < 16; ++gg) mm = fmaxf(mm, redBm[gg][h]);
    float z = 0.f, s2 = 0.f;
    float io[16];
    #pragma unroll
    for (int dd = 0; dd < 16; ++dd) io[dd] = 0.f;
    for (int k = ks; k < ks + 32; ++k) {
      if (!ams[k]) continue;
      const float p = __expf(__bfloat162float(sB[k]) - mm);
      z += p; s2 += p * p;
      const float4* hp = (const float4*)(pf + (size_t)(b * 512 + k) * 256 + h * 16);
      const float4 v0 = hp[0], v1 = hp[1], v2 = hp[2], v3 = hp[3];
      io[0]+=p*v0.x;  io[1]+=p*v0.y;  io[2]+=p*v0.z;  io[3]+=p*v0.w;
      io[4]+=p*v1.x;  io[5]+=p*v1.y;  io[6]+=p*v1.z;  io[7]+=p*v1.w;
      io[8]+=p*v2.x;  io[9]+=p*v2.y;  io[10]+=p*v2.z; io[11]+=p*v2.w;
      io[12]+=p*v3.x; io[13]+=p*v3.y; io[14]+=p*v3.z; io[15]+=p*v3.w;
    }
    redBz[g][h] = z; redBs[g][h] = s2;
    #pragma unroll
    for (int dd = 0; dd < 16; ++dd) ioB[g][h][dd] = io[dd];
    __syncthreads();
    const int h2 = tid >> 4, dd = tid & 15;
    float zt = 0.f, s2t = 0.f, iot = 0.f;
    #pragma unroll
    for (int gg = 0; gg < 16; ++gg) {
      zt += redBz[gg][h2]; s2t += redBs[gg][h2]; iot += ioB[gg][h2][dd];
    }
    const float inv = 1.f / zt;
    io_s[h2 * 16 + dd] = iot * sqrtf(s2t) * inv * inv;
  }
  __syncthreads();
  {   // inv_out = io @ inv_out_w + iob
    float a = iob[tid];
    for (int k = 0; k < 256; ++k) a += io_s[k] * iow[k * 256 + tid];
    out[98304 + (size_t)bq * 256 + tid] = a;
  }
}

// ===================== launch =====================
extern "C" void kernel_launch(void* const* d_in, const int* in_sizes, int n_in,
                              void* d_out, int out_size, void* d_ws, size_t ws_size,
                              hipStream_t stream) {
  const float* equis      = (const float*)d_in[0];
  const float* invs       = (const float*)d_in[1];
  const float* cond_equis = (const float*)d_in[2];
  const float* cond_invs  = (const float*)d_in[3];
  const float* edges      = (const float*)d_in[4];
  const int*   adj        = (const int*)d_in[5];
  const float* q_w  = (const float*)d_in[6];
  const float* q_b  = (const float*)d_in[7];
  const float* k_w  = (const float*)d_in[8];
  const float* k_b  = (const float*)d_in[9];
  const float* w1   = (const float*)d_in[10];
  const float* b1   = (const float*)d_in[11];
  const float* w2   = (const float*)d_in[12];
  const float* b2   = (const float*)d_in[13];
  const float* equi_in_w  = (const float*)d_in[14];
  const float* equi_out_w = (const float*)d_in[15];
  const float* inv_in_w   = (const float*)d_in[16];
  const float* inv_in_b   = (const float*)d_in[17];
  const float* inv_out_w  = (const float*)d_in[18];
  const float* inv_out_b  = (const float*)d_in[19];

  float* out = (float*)d_out;
  float* ws  = (float*)d_ws;
  // ws layout: [w1t bf16 65536][w2t bf16 36864] = 51200 floats, then fp32 tensors, then sct bf16
  unsigned short* w1t = (unsigned short*)ws;
  unsigned short* w2t = w1t + 65536;
  float* qm   = ws + 51200;
  float* km   = qm + 32768;
  float* proj = km + 65536;
  float* pf   = proj + 196608;
  __hip_bfloat16* sct = (__hip_bfloat16*)(pf + 262144);   // 512*80*512 bf16 = 41.9 MB

  transpose_w_kernel<<<256, 256, 0, stream>>>(w1, w1t, 256);
  transpose_w_kernel<<<144, 256, 0, stream>>>(w2, w2t, 144);
  rowgemm_kernel<<<512,  64,  0, stream>>>(invs,       q_w,       q_b,       qm,   256, 64);
  rowgemm_kernel<<<1024, 64,  0, stream>>>(cond_invs,  k_w,       k_b,       km,   256, 64);
  rowgemm_kernel<<<3072, 64,  0, stream>>>(cond_equis, equi_in_w, nullptr,   proj, 64,  64);
  rowgemm_kernel<<<1024, 256, 0, stream>>>(cond_invs,  inv_in_w,  inv_in_b,  pf,   256, 256);

  msg_kernel<<<2048, 512, 0, stream>>>(equis, cond_equis, edges, qm, km,
                                       w1t, b1, w2t, b2,
                                       out + 229376 /*edge_out*/, sct);

  attn_kernel<<<512, 256, 0, stream>>>(sct, adj, proj, pf,
                                       equi_out_w, inv_out_w, inv_out_b, out);
}

// Round 4
// 225.297 us; speedup vs baseline: 5.9516x; 1.4234x over previous
//
#include <hip/hip_runtime.h>
#include <hip/hip_bf16.h>

#define DEVINL static __device__ __forceinline__

typedef __attribute__((ext_vector_type(8))) short bf16x8;
typedef __attribute__((ext_vector_type(4))) float f32x4;
typedef __attribute__((ext_vector_type(4))) unsigned short us4;

DEVINL float siluf(float x) { return x / (1.0f + __expf(-x)); }
DEVINL unsigned short bfb(float x) { __hip_bfloat16 h = __float2bfloat16(x); return *(unsigned short*)&h; }
DEVINL float b2f(unsigned short u) { return __uint_as_float(((unsigned int)u) << 16); }

// ===================== prep: transpose w1,w2 to bf16 k-major =====================
// grid 400: c<256 -> w1t row c ; else w2t row c-256. block 256 (= K)
__global__ void prep_w_kernel(const float* __restrict__ w1, const float* __restrict__ w2,
                              unsigned short* __restrict__ w1t, unsigned short* __restrict__ w2t) {
  const int c = blockIdx.x, k = threadIdx.x;
  if (c < 256) w1t[(size_t)c * 256 + k] = bfb(w1[(size_t)k * 256 + c]);
  else         w2t[(size_t)(c - 256) * 256 + k] = bfb(w2[(size_t)k * 144 + (c - 256)]);
}

// ===================== prep: q_msg / k_msg (merged) =====================
// grid 1536, block 64: r<512 -> qm row r ; else km row r-512
__global__ void qk_kernel(const float* __restrict__ invs, const float* __restrict__ cond_invs,
                          const float* __restrict__ qw, const float* __restrict__ qb,
                          const float* __restrict__ kw, const float* __restrict__ kb2,
                          float* __restrict__ qm, float* __restrict__ km) {
  __shared__ float srow[256];
  const int r = blockIdx.x;
  const float* in; const float* w; const float* bias; float* out; int row;
  if (r < 512) { in = invs;      w = qw; bias = qb;  out = qm; row = r; }
  else         { in = cond_invs; w = kw; bias = kb2; out = km; row = r - 512; }
  for (int k = threadIdx.x; k < 256; k += 64) srow[k] = in[(size_t)row * 256 + k];
  __syncthreads();
  const int c = threadIdx.x;
  float acc = bias[c];
  for (int k = 0; k < 256; ++k) acc += srow[k] * w[(size_t)k * 64 + c];
  out[(size_t)row * 64 + c] = acc;
}

// ===================== prep: proj transposed k-major =====================
// grid 3072 (= B*NC*3), block 64. projt[((b*3+x)*64+c)*512 + kn]
__global__ void projt_kernel(const float* __restrict__ ce, const float* __restrict__ eiw,
                             float* __restrict__ projt) {
  __shared__ float srow[64];
  const int r = blockIdx.x;
  const int b = r / 1536, rr = r % 1536, kn = rr / 3, x = rr % 3;
  srow[threadIdx.x] = ce[(size_t)r * 64 + threadIdx.x];
  __syncthreads();
  const int c = threadIdx.x;
  float acc = 0.f;
  for (int k = 0; k < 64; ++k) acc += srow[k] * eiw[(size_t)k * 64 + c];
  projt[((size_t)(b * 3 + x) * 64 + c) * 512 + kn] = acc;
}

// ===================== prep: pf transposed k-major =====================
// grid 1024 (= B*NC), block 256. pft[(b*256+c)*512 + kn]
__global__ void pft_kernel(const float* __restrict__ ci, const float* __restrict__ iiw,
                           const float* __restrict__ iib, float* __restrict__ pft) {
  __shared__ float srow[256];
  const int r = blockIdx.x, b = r >> 9, kn = r & 511;
  srow[threadIdx.x] = ci[(size_t)r * 256 + threadIdx.x];
  __syncthreads();
  const int c = threadIdx.x;
  float acc = iib[c];
  for (int k = 0; k < 256; ++k) acc += srow[k] * iiw[(size_t)k * 256 + c];
  pft[((size_t)(b * 256) + c) * 512 + kn] = acc;
}

// ===================== main message kernel (MFMA, 4 waves, 64-row tiles) =====================
// grid = 512 (b,q) x 8 k-tiles of 64 rows; block = 256 threads (4 waves, each a 64-FF quarter)
__global__ __launch_bounds__(256, 4) void msg_kernel(
    const float* __restrict__ equis, const float* __restrict__ cond_equis,
    const float* __restrict__ edges,
    const float* __restrict__ qm, const float* __restrict__ km,
    const unsigned short* __restrict__ w1t, const float* __restrict__ b1,
    const unsigned short* __restrict__ w2t, const float* __restrict__ b2,
    float* __restrict__ edge_out, __hip_bfloat16* __restrict__ sct) {
  __shared__ __align__(16) unsigned short tile[64][264];   // feats, then h (reused)
  __shared__ __align__(16) float eq_s[192];
  __shared__ __align__(16) float qm_s[64];

  const int bq = blockIdx.x >> 3;     // b*256+q
  const int b  = bq >> 8;
  const int k0 = (blockIdx.x & 7) * 64;
  const int tid = threadIdx.x;

  if (tid < 192) eq_s[tid] = equis[(size_t)bq * 192 + tid];
  else           qm_s[tid - 192] = qm[(size_t)bq * 64 + (tid - 192)];
  __syncthreads();

  // ---- build feats tile in bf16: cols [qmsg | kmsg | dot | edges] ----
  {
    const int r = tid & 63, cq = tid >> 6;   // wave-uniform column quarter
    const int kg = k0 + r;
    if (cq == 0) {
      #pragma unroll
      for (int j = 0; j < 16; ++j) {
        const float4 v = *(const float4*)&qm_s[j * 4];
        us4 u = { bfb(v.x), bfb(v.y), bfb(v.z), bfb(v.w) };
        *(us4*)&tile[r][j * 4] = u;
      }
    } else if (cq == 1) {
      const float* kmr = km + (size_t)(b * 512 + kg) * 64;
      #pragma unroll
      for (int j = 0; j < 16; ++j) {
        const float4 v = *(const float4*)&kmr[j * 4];
        us4 u = { bfb(v.x), bfb(v.y), bfb(v.z), bfb(v.w) };
        *(us4*)&tile[r][64 + j * 4] = u;
      }
    } else if (cq == 2) {
      const float* cer = cond_equis + (size_t)(b * 512 + kg) * 192;
      #pragma unroll
      for (int j = 0; j < 16; ++j) {
        const int d = j * 4;
        const float4 c0 = *(const float4*)&cer[d];
        const float4 c1 = *(const float4*)&cer[64 + d];
        const float4 c2 = *(const float4*)&cer[128 + d];
        const float4 e0 = *(const float4*)&eq_s[d];
        const float4 e1 = *(const float4*)&eq_s[64 + d];
        const float4 e2 = *(const float4*)&eq_s[128 + d];
        float4 v;
        v.x = e0.x * c0.x + e1.x * c1.x + e2.x * c2.x;
        v.y = e0.y * c0.y + e1.y * c1.y + e2.y * c2.y;
        v.z = e0.z * c0.z + e1.z * c1.z + e2.z * c2.z;
        v.w = e0.w * c0.w + e1.w * c1.w + e2.w * c2.w;
        us4 u = { bfb(v.x), bfb(v.y), bfb(v.z), bfb(v.w) };
        *(us4*)&tile[r][128 + d] = u;
      }
    } else {
      const float* edr = edges + ((size_t)bq * 512 + kg) * 64;
      #pragma unroll
      for (int j = 0; j < 16; ++j) {
        const float4 v = *(const float4*)&edr[j * 4];
        us4 u = { bfb(v.x), bfb(v.y), bfb(v.z), bfb(v.w) };
        *(us4*)&tile[r][192 + j * 4] = u;
      }
    }
  }
  __syncthreads();

  const int lane = tid & 63;
  const int wn = tid >> 6;                  // FF quarter
  const int lj  = lane & 15;
  const int lkb = (lane >> 4) * 8;
  const int lr4 = (lane >> 4) * 4;

  // ---- GEMM1 (transposed): D1[c][r], c in [wn*64,+64), r in [0,64) ----
  f32x4 acc[4][4];
  #pragma unroll
  for (int ct = 0; ct < 4; ++ct) {
    const float4 bb = *(const float4*)&b1[wn * 64 + ct * 16 + lr4];
    #pragma unroll
    for (int rt = 0; rt < 4; ++rt) { acc[ct][rt][0] = bb.x; acc[ct][rt][1] = bb.y; acc[ct][rt][2] = bb.z; acc[ct][rt][3] = bb.w; }
  }
  #pragma unroll 2
  for (int kk = 0; kk < 8; ++kk) {
    bf16x8 fb[4], wa[4];
    #pragma unroll
    for (int rt = 0; rt < 4; ++rt)
      fb[rt] = *(const bf16x8*)&tile[rt * 16 + lj][kk * 32 + lkb];
    #pragma unroll
    for (int ct = 0; ct < 4; ++ct)
      wa[ct] = *(const bf16x8*)&w1t[(size_t)(wn * 64 + ct * 16 + lj) * 256 + kk * 32 + lkb];
    #pragma unroll
    for (int ct = 0; ct < 4; ++ct)
      #pragma unroll
      for (int rt = 0; rt < 4; ++rt)
        acc[ct][rt] = __builtin_amdgcn_mfma_f32_16x16x32_bf16(wa[ct], fb[rt], acc[ct][rt], 0, 0, 0);
  }
  __syncthreads();   // everyone done reading feats

  // ---- h = silu(acc) -> bf16 back into tile ----
  #pragma unroll
  for (int ct = 0; ct < 4; ++ct)
    #pragma unroll
    for (int rt = 0; rt < 4; ++rt) {
      us4 u = { bfb(siluf(acc[ct][rt][0])), bfb(siluf(acc[ct][rt][1])),
                bfb(siluf(acc[ct][rt][2])), bfb(siluf(acc[ct][rt][3])) };
      *(us4*)&tile[rt * 16 + lj][wn * 64 + ct * 16 + lr4] = u;
    }
  __syncthreads();

  // ---- GEMM2 (transposed): 9 channel-tiles, t = it*4 + wn ----
  {
    f32x4 a2[3][4];
    #pragma unroll
    for (int it = 0; it < 3; ++it) {
      const int t = it * 4 + wn;
      if (t < 9) {
        const float4 bb = *(const float4*)&b2[t * 16 + lr4];
        #pragma unroll
        for (int rt = 0; rt < 4; ++rt) { a2[it][rt][0] = bb.x; a2[it][rt][1] = bb.y; a2[it][rt][2] = bb.z; a2[it][rt][3] = bb.w; }
      }
    }
    #pragma unroll 2
    for (int kk = 0; kk < 8; ++kk) {
      bf16x8 fb[4];
      #pragma unroll
      for (int rt = 0; rt < 4; ++rt)
        fb[rt] = *(const bf16x8*)&tile[rt * 16 + lj][kk * 32 + lkb];
      #pragma unroll
      for (int it = 0; it < 3; ++it) {
        const int t = it * 4 + wn;
        if (t < 9) {
          const bf16x8 wa = *(const bf16x8*)&w2t[(size_t)(t * 16 + lj) * 256 + kk * 32 + lkb];
          #pragma unroll
          for (int rt = 0; rt < 4; ++rt)
            a2[it][rt] = __builtin_amdgcn_mfma_f32_16x16x32_bf16(wa, fb[rt], a2[it][rt], 0, 0, 0);
        }
      }
    }
    #pragma unroll
    for (int it = 0; it < 3; ++it) {
      const int t = it * 4 + wn;
      if (t < 9) {
        if (t < 5) {
          #pragma unroll
          for (int rt = 0; rt < 4; ++rt) {
            const int kgl = k0 + rt * 16 + lj;
            __hip_bfloat16* sp = sct + ((size_t)bq * 80 + t * 16 + lr4) * 512 + kgl;
            #pragma unroll
            for (int rr = 0; rr < 4; ++rr) sp[rr * 512] = __float2bfloat16(a2[it][rt][rr]);
          }
        } else {
          #pragma unroll
          for (int rt = 0; rt < 4; ++rt) {
            const int kgl = k0 + rt * 16 + lj;
            float4 v; v.x = a2[it][rt][0]; v.y = a2[it][rt][1]; v.z = a2[it][rt][2]; v.w = a2[it][rt][3];
            *(float4*)&edge_out[((size_t)bq * 512 + kgl) * 64 + (t * 16 - 80) + lr4] = v;
          }
        }
      }
    }
  }
}

// ===================== attention + outputs (coalesced, shfl reductions) =====================
// one block (512 thr = 8 waves) per (b,q); lane = k/8 (k-contiguous loads)
__global__ __launch_bounds__(512) void attn_kernel(
    const __hip_bfloat16* __restrict__ sct, const int* __restrict__ adj,
    const float* __restrict__ projt, const float* __restrict__ pft,
    const float* __restrict__ eow, const float* __restrict__ iow,
    const float* __restrict__ iob, float* __restrict__ out) {
  __shared__ float eo_s[3][64];
  __shared__ float io_s[256];

  const int bq = blockIdx.x, b = bq >> 8;
  const int tid = threadIdx.x, lane = tid & 63, w = tid >> 6;
  const int kb = lane * 8;

  // per-lane adjacency bitmask for k = kb..kb+7
  const int4 aj0 = *(const int4*)&adj[(size_t)bq * 512 + kb];
  const int4 aj1 = *(const int4*)&adj[(size_t)bq * 512 + kb + 4];
  const unsigned int mk = (aj0.x > 0 ? 1u : 0) | (aj0.y > 0 ? 2u : 0) | (aj0.z > 0 ? 4u : 0) | (aj0.w > 0 ? 8u : 0)
                        | (aj1.x > 0 ? 16u : 0) | (aj1.y > 0 ? 32u : 0) | (aj1.z > 0 ? 64u : 0) | (aj1.w > 0 ? 128u : 0);

  // ---- Phase A: equi channels d = w*8 .. w*8+7 ----
  for (int dd = 0; dd < 8; ++dd) {
    const int d = w * 8 + dd;
    const bf16x8 s8 = *(const bf16x8*)&sct[((size_t)bq * 80 + d) * 512 + kb];
    float v[8];
    #pragma unroll
    for (int j = 0; j < 8; ++j)
      v[j] = ((mk >> j) & 1) ? b2f((unsigned short)s8[j]) : -1e30f;
    float m = v[0];
    #pragma unroll
    for (int j = 1; j < 8; ++j) m = fmaxf(m, v[j]);
    #pragma unroll
    for (int off = 32; off; off >>= 1) m = fmaxf(m, __shfl_xor(m, off, 64));
    float p[8], z = 0.f, s2 = 0.f;
    #pragma unroll
    for (int j = 0; j < 8; ++j) { const float e = __expf(v[j] - m); p[j] = e; z += e; s2 += e * e; }
    float ax[3];
    #pragma unroll
    for (int x = 0; x < 3; ++x) {
      const float* pr = projt + ((size_t)(b * 3 + x) * 64 + d) * 512 + kb;
      const float4 w0 = *(const float4*)pr;
      const float4 w1v = *(const float4*)(pr + 4);
      ax[x] = p[0] * w0.x + p[1] * w0.y + p[2] * w0.z + p[3] * w0.w
            + p[4] * w1v.x + p[5] * w1v.y + p[6] * w1v.z + p[7] * w1v.w;
    }
    #pragma unroll
    for (int off = 32; off; off >>= 1) {
      z += __shfl_xor(z, off, 64); s2 += __shfl_xor(s2, off, 64);
      ax[0] += __shfl_xor(ax[0], off, 64); ax[1] += __shfl_xor(ax[1], off, 64); ax[2] += __shfl_xor(ax[2], off, 64);
    }
    if (lane == 0) {
      const float sc = sqrtf(s2) / (z * z);
      eo_s[0][d] = ax[0] * sc; eo_s[1][d] = ax[1] * sc; eo_s[2][d] = ax[2] * sc;
    }
  }

  // ---- Phase B: inv heads h = w*2 .. w*2+1 ----
  #pragma unroll
  for (int hh = 0; hh < 2; ++hh) {
    const int h = w * 2 + hh;
    const bf16x8 s8 = *(const bf16x8*)&sct[((size_t)bq * 80 + 64 + h) * 512 + kb];
    float v[8];
    #pragma unroll
    for (int j = 0; j < 8; ++j)
      v[j] = ((mk >> j) & 1) ? b2f((unsigned short)s8[j]) : -1e30f;
    float m = v[0];
    #pragma unroll
    for (int j = 1; j < 8; ++j) m = fmaxf(m, v[j]);
    #pragma unroll
    for (int off = 32; off; off >>= 1) m = fmaxf(m, __shfl_xor(m, off, 64));
    float p[8], z = 0.f, s2 = 0.f;
    #pragma unroll
    for (int j = 0; j < 8; ++j) { const float e = __expf(v[j] - m); p[j] = e; z += e; s2 += e * e; }
    f32x4 io[4];
    #pragma unroll
    for (int d4 = 0; d4 < 4; ++d4)
      #pragma unroll
      for (int di = 0; di < 4; ++di) {
        const float* pr = pft + ((size_t)(b * 256) + h * 16 + d4 * 4 + di) * 512 + kb;
        const float4 w0 = *(const float4*)pr;
        const float4 w1v = *(const float4*)(pr + 4);
        io[d4][di] = p[0] * w0.x + p[1] * w0.y + p[2] * w0.z + p[3] * w0.w
                   + p[4] * w1v.x + p[5] * w1v.y + p[6] * w1v.z + p[7] * w1v.w;
      }
    #pragma unroll
    for (int off = 32; off; off >>= 1) {
      z += __shfl_xor(z, off, 64); s2 += __shfl_xor(s2, off, 64);
      #pragma unroll
      for (int d4 = 0; d4 < 4; ++d4)
        #pragma unroll
        for (int di = 0; di < 4; ++di)
          io[d4][di] += __shfl_xor(io[d4][di], off, 64);
    }
    if (lane == 0) {
      const float sc = sqrtf(s2) / (z * z);
      #pragma unroll
      for (int d4 = 0; d4 < 4; ++d4) {
        float4 vv; vv.x = io[d4][0] * sc; vv.y = io[d4][1] * sc; vv.z = io[d4][2] * sc; vv.w = io[d4][3] * sc;
        *(float4*)&io_s[h * 16 + d4 * 4] = vv;
      }
    }
  }
  __syncthreads();

  if (tid < 192) {   // equi_out = eo @ equi_out_w
    const int x = tid >> 6, e = tid & 63;
    float a = 0.f;
    for (int d = 0; d < 64; ++d) a += eo_s[x][d] * eow[(size_t)d * 64 + e];
    out[(size_t)bq * 192 + x * 64 + e] = a;
  }
  if (tid < 256) {   // inv_out = io @ inv_out_w + iob
    float a = iob[tid];
    for (int k = 0; k < 256; ++k) a += io_s[k] * iow[(size_t)k * 256 + tid];
    out[98304 + (size_t)bq * 256 + tid] = a;
  }
}

// ===================== launch =====================
extern "C" void kernel_launch(void* const* d_in, const int* in_sizes, int n_in,
                              void* d_out, int out_size, void* d_ws, size_t ws_size,
                              hipStream_t stream) {
  const float* equis      = (const float*)d_in[0];
  const float* invs       = (const float*)d_in[1];
  const float* cond_equis = (const float*)d_in[2];
  const float* cond_invs  = (const float*)d_in[3];
  const float* edges      = (const float*)d_in[4];
  const int*   adj        = (const int*)d_in[5];
  const float* q_w  = (const float*)d_in[6];
  const float* q_b  = (const float*)d_in[7];
  const float* k_w  = (const float*)d_in[8];
  const float* k_b  = (const float*)d_in[9];
  const float* w1   = (const float*)d_in[10];
  const float* b1   = (const float*)d_in[11];
  const float* w2   = (const float*)d_in[12];
  const float* b2   = (const float*)d_in[13];
  const float* equi_out_w = (const float*)d_in[15];
  const float* inv_in_w   = (const float*)d_in[16];
  const float* inv_in_b   = (const float*)d_in[17];
  const float* inv_out_w  = (const float*)d_in[18];
  const float* inv_out_b  = (const float*)d_in[19];
  const float* equi_in_w  = (const float*)d_in[14];

  float* out = (float*)d_out;
  float* ws  = (float*)d_ws;
  unsigned short* w1t = (unsigned short*)ws;             // 65536 us
  unsigned short* w2t = w1t + 65536;                     // 36864 us  (-> 51200 floats)
  float* qm    = ws + 51200;                             // 32768
  float* km    = qm + 32768;                             // 65536
  float* projt = km + 65536;                             // 196608  [b][x][d][512]
  float* pft   = projt + 196608;                         // 262144  [b][ch][512]
  __hip_bfloat16* sct = (__hip_bfloat16*)(pft + 262144); // 512*80*512 bf16 = 41.9 MB

  prep_w_kernel<<<400, 256, 0, stream>>>(w1, w2, w1t, w2t);
  qk_kernel<<<1536, 64, 0, stream>>>(invs, cond_invs, q_w, q_b, k_w, k_b, qm, km);
  projt_kernel<<<3072, 64, 0, stream>>>(cond_equis, equi_in_w, projt);
  pft_kernel<<<1024, 256, 0, stream>>>(cond_invs, inv_in_w, inv_in_b, pft);

  msg_kernel<<<4096, 256, 0, stream>>>(equis, cond_equis, edges, qm, km,
                                       w1t, b1, w2t, b2,
                                       out + 229376 /*edge_out*/, sct);

  attn_kernel<<<512, 512, 0, stream>>>(sct, adj, projt, pft,
                                       equi_out_w, inv_out_w, inv_out_b, out);
}

// Round 5
// 192.488 us; speedup vs baseline: 6.9661x; 1.1704x over previous
//
#include <hip/hip_runtime.h>
#include <hip/hip_bf16.h>

#define DEVINL static __device__ __forceinline__

typedef __attribute__((ext_vector_type(8))) short bf16x8;
typedef __attribute__((ext_vector_type(4))) float f32x4;
typedef __attribute__((ext_vector_type(4))) unsigned short us4;

DEVINL float siluf(float x) { return x / (1.0f + __expf(-x)); }
DEVINL unsigned short bfb(float x) { __hip_bfloat16 h = __float2bfloat16(x); return *(unsigned short*)&h; }
DEVINL float b2f(unsigned short u) { return __uint_as_float(((unsigned int)u) << 16); }

// ===================== prep: transpose w1,w2 to bf16 k-major =====================
__global__ void prep_w_kernel(const float* __restrict__ w1, const float* __restrict__ w2,
                              unsigned short* __restrict__ w1t, unsigned short* __restrict__ w2t) {
  const int c = blockIdx.x, k = threadIdx.x;
  if (c < 256) w1t[(size_t)c * 256 + k] = bfb(w1[(size_t)k * 256 + c]);
  else         w2t[(size_t)(c - 256) * 256 + k] = bfb(w2[(size_t)k * 144 + (c - 256)]);
}

// ===================== prep: q_msg / k_msg (merged) =====================
__global__ void qk_kernel(const float* __restrict__ invs, const float* __restrict__ cond_invs,
                          const float* __restrict__ qw, const float* __restrict__ qb,
                          const float* __restrict__ kw, const float* __restrict__ kb2,
                          float* __restrict__ qm, float* __restrict__ km) {
  __shared__ float srow[256];
  const int r = blockIdx.x;
  const float* in; const float* w; const float* bias; float* out; int row;
  if (r < 512) { in = invs;      w = qw; bias = qb;  out = qm; row = r; }
  else         { in = cond_invs; w = kw; bias = kb2; out = km; row = r - 512; }
  for (int k = threadIdx.x; k < 256; k += 64) srow[k] = in[(size_t)row * 256 + k];
  __syncthreads();
  const int c = threadIdx.x;
  float acc = bias[c];
  for (int k = 0; k < 256; ++k) acc += srow[k] * w[(size_t)k * 64 + c];
  out[(size_t)row * 64 + c] = acc;
}

// ===================== prep: proj transposed k-major =====================
__global__ void projt_kernel(const float* __restrict__ ce, const float* __restrict__ eiw,
                             float* __restrict__ projt) {
  __shared__ float srow[64];
  const int r = blockIdx.x;
  const int b = r / 1536, rr = r % 1536, kn = rr / 3, x = rr % 3;
  srow[threadIdx.x] = ce[(size_t)r * 64 + threadIdx.x];
  __syncthreads();
  const int c = threadIdx.x;
  float acc = 0.f;
  for (int k = 0; k < 64; ++k) acc += srow[k] * eiw[(size_t)k * 64 + c];
  projt[((size_t)(b * 3 + x) * 64 + c) * 512 + kn] = acc;
}

// ===================== prep: pf transposed k-major =====================
__global__ void pft_kernel(const float* __restrict__ ci, const float* __restrict__ iiw,
                           const float* __restrict__ iib, float* __restrict__ pft) {
  __shared__ float srow[256];
  const int r = blockIdx.x, b = r >> 9, kn = r & 511;
  srow[threadIdx.x] = ci[(size_t)r * 256 + threadIdx.x];
  __syncthreads();
  const int c = threadIdx.x;
  float acc = iib[c];
  for (int k = 0; k < 256; ++k) acc += srow[k] * iiw[(size_t)k * 256 + c];
  pft[((size_t)(b * 256) + c) * 512 + kn] = acc;
}

// ===================== main message kernel =====================
// grid = 512 (b,q) x 4 k-tiles of 128 rows; block = 256 threads (4 waves, each 64 FF ch x 128 rows)
__global__ __launch_bounds__(256, 2) void msg_kernel(
    const float* __restrict__ equis, const float* __restrict__ cond_equis,
    const float* __restrict__ edges,
    const float* __restrict__ qm, const float* __restrict__ km,
    const unsigned short* __restrict__ w1t, const float* __restrict__ b1,
    const unsigned short* __restrict__ w2t, const float* __restrict__ b2,
    float* __restrict__ edge_out, __hip_bfloat16* __restrict__ sct) {
  __shared__ __align__(16) unsigned short tile[128][264];   // feats, then h (reused)
  __shared__ __align__(16) float eq_s[192];
  __shared__ __align__(16) float qm_s[64];

  const int bq = blockIdx.x >> 2;     // b*256+q
  const int b  = bq >> 8;
  const int k0 = (blockIdx.x & 2) * 128;   // (blockIdx&3)>>1 *... see below
  const int k0r = (blockIdx.x & 3) * 128;
  (void)k0;
  const int tid = threadIdx.x;

  if (tid < 192) eq_s[tid] = equis[(size_t)bq * 192 + tid];
  else           qm_s[tid - 192] = qm[(size_t)bq * 64 + (tid - 192)];
  __syncthreads();

  // ---- build feats tile: 256 thr, r = tid&127, half = tid>>7 (wave-uniform) ----
  {
    const int r = tid & 127, half = tid >> 7;
    const int kg = k0r + r;
    if (half == 0) {
      #pragma unroll
      for (int j = 0; j < 16; ++j) {       // qmsg cols 0..63
        const float4 v = *(const float4*)&qm_s[j * 4];
        us4 u = { bfb(v.x), bfb(v.y), bfb(v.z), bfb(v.w) };
        *(us4*)&tile[r][j * 4] = u;
      }
      const float* cer = cond_equis + (size_t)(b * 512 + kg) * 192;
      #pragma unroll
      for (int j = 0; j < 16; ++j) {       // dot cols 128..191
        const int d = j * 4;
        const float4 c0 = *(const float4*)&cer[d];
        const float4 c1 = *(const float4*)&cer[64 + d];
        const float4 c2 = *(const float4*)&cer[128 + d];
        const float4 e0 = *(const float4*)&eq_s[d];
        const float4 e1 = *(const float4*)&eq_s[64 + d];
        const float4 e2 = *(const float4*)&eq_s[128 + d];
        float4 v;
        v.x = e0.x * c0.x + e1.x * c1.x + e2.x * c2.x;
        v.y = e0.y * c0.y + e1.y * c1.y + e2.y * c2.y;
        v.z = e0.z * c0.z + e1.z * c1.z + e2.z * c2.z;
        v.w = e0.w * c0.w + e1.w * c1.w + e2.w * c2.w;
        us4 u = { bfb(v.x), bfb(v.y), bfb(v.z), bfb(v.w) };
        *(us4*)&tile[r][128 + d] = u;
      }
    } else {
      const float* kmr = km + (size_t)(b * 512 + kg) * 64;
      #pragma unroll
      for (int j = 0; j < 16; ++j) {       // kmsg cols 64..127
        const float4 v = *(const float4*)&kmr[j * 4];
        us4 u = { bfb(v.x), bfb(v.y), bfb(v.z), bfb(v.w) };
        *(us4*)&tile[r][64 + j * 4] = u;
      }
      const float* edr = edges + ((size_t)bq * 512 + kg) * 64;
      #pragma unroll
      for (int j = 0; j < 16; ++j) {       // edges cols 192..255
        const float4 v = *(const float4*)&edr[j * 4];
        us4 u = { bfb(v.x), bfb(v.y), bfb(v.z), bfb(v.w) };
        *(us4*)&tile[r][192 + j * 4] = u;
      }
    }
  }
  __syncthreads();

  const int lane = tid & 63;
  const int wn = tid >> 6;                  // wave = FF quarter (GEMM1) / tile set (GEMM2)
  const int lj  = lane & 15;
  const int lkb = (lane >> 4) * 8;
  const int lr4 = (lane >> 4) * 4;

// ---- weight-load macros (depth-1 register double buffer, all static idx) ----
#define LOADW1(BUF, KK) { \
    _Pragma("unroll") for (int ct = 0; ct < 4; ++ct) \
      BUF[ct] = *(const bf16x8*)&w1t[(size_t)(wn * 64 + ct * 16 + lj) * 256 + (KK) * 32 + lkb]; }

#define G1STEP(KK, CUR, NXT, DOPF) { \
    if (DOPF) { LOADW1(NXT, (KK) + 1); } \
    _Pragma("unroll") for (int g = 0; g < 2; ++g) { \
      bf16x8 fb[4]; \
      _Pragma("unroll") for (int r4 = 0; r4 < 4; ++r4) \
        fb[r4] = *(const bf16x8*)&tile[(g * 4 + r4) * 16 + lj][(KK) * 32 + lkb]; \
      _Pragma("unroll") for (int ct = 0; ct < 4; ++ct) { \
        _Pragma("unroll") for (int r4 = 0; r4 < 4; ++r4) \
          acc[ct][g * 4 + r4] = __builtin_amdgcn_mfma_f32_16x16x32_bf16(CUR[ct], fb[r4], acc[ct][g * 4 + r4], 0, 0, 0); \
      } \
    } }

  // ---- GEMM1: D1[c][r], c in [wn*64,+64), r in [0,128) ----
  f32x4 acc[4][8];
  #pragma unroll
  for (int ct = 0; ct < 4; ++ct) {
    const float4 bb = *(const float4*)&b1[wn * 64 + ct * 16 + lr4];
    #pragma unroll
    for (int rt = 0; rt < 8; ++rt) { acc[ct][rt][0] = bb.x; acc[ct][rt][1] = bb.y; acc[ct][rt][2] = bb.z; acc[ct][rt][3] = bb.w; }
  }
  {
    bf16x8 waA[4], waB[4];
    LOADW1(waA, 0);
    G1STEP(0, waA, waB, 1)
    G1STEP(1, waB, waA, 1)
    G1STEP(2, waA, waB, 1)
    G1STEP(3, waB, waA, 1)
    G1STEP(4, waA, waB, 1)
    G1STEP(5, waB, waA, 1)
    G1STEP(6, waA, waB, 1)
    G1STEP(7, waB, waA, 0)
  }
  __syncthreads();   // all waves done reading feats

  // ---- h = silu(acc) -> bf16 back into tile ----
  #pragma unroll
  for (int ct = 0; ct < 4; ++ct)
    #pragma unroll
    for (int rt = 0; rt < 8; ++rt) {
      us4 u = { bfb(siluf(acc[ct][rt][0])), bfb(siluf(acc[ct][rt][1])),
                bfb(siluf(acc[ct][rt][2])), bfb(siluf(acc[ct][rt][3])) };
      *(us4*)&tile[rt * 16 + lj][wn * 64 + ct * 16 + lr4] = u;
    }
  __syncthreads();

// ---- GEMM2 macros ----
#define LOADW2(BUF, KK) { \
    _Pragma("unroll") for (int it = 0; it < 3; ++it) { \
      const int t = it * 4 + wn; \
      if (t < 9) BUF[it] = *(const bf16x8*)&w2t[(size_t)(t * 16 + lj) * 256 + (KK) * 32 + lkb]; } }

#define G2STEP(KK, CUR, NXT, DOPF) { \
    if (DOPF) { LOADW2(NXT, (KK) + 1); } \
    _Pragma("unroll") for (int g = 0; g < 2; ++g) { \
      bf16x8 fb[4]; \
      _Pragma("unroll") for (int r4 = 0; r4 < 4; ++r4) \
        fb[r4] = *(const bf16x8*)&tile[(g * 4 + r4) * 16 + lj][(KK) * 32 + lkb]; \
      _Pragma("unroll") for (int it = 0; it < 3; ++it) { \
        const int t = it * 4 + wn; \
        if (t < 9) { \
          _Pragma("unroll") for (int r4 = 0; r4 < 4; ++r4) \
            a2[it][g * 4 + r4] = __builtin_amdgcn_mfma_f32_16x16x32_bf16(CUR[it], fb[r4], a2[it][g * 4 + r4], 0, 0, 0); \
        } \
      } \
    } }

  // ---- GEMM2: 9 channel-tiles, t = it*4 + wn ----
  {
    f32x4 a2[3][8];
    #pragma unroll
    for (int it = 0; it < 3; ++it) {
      const int t = it * 4 + wn;
      if (t < 9) {
        const float4 bb = *(const float4*)&b2[t * 16 + lr4];
        #pragma unroll
        for (int rt = 0; rt < 8; ++rt) { a2[it][rt][0] = bb.x; a2[it][rt][1] = bb.y; a2[it][rt][2] = bb.z; a2[it][rt][3] = bb.w; }
      }
    }
    {
      bf16x8 wbA[3], wbB[3];
      LOADW2(wbA, 0);
      G2STEP(0, wbA, wbB, 1)
      G2STEP(1, wbB, wbA, 1)
      G2STEP(2, wbA, wbB, 1)
      G2STEP(3, wbB, wbA, 1)
      G2STEP(4, wbA, wbB, 1)
      G2STEP(5, wbB, wbA, 1)
      G2STEP(6, wbA, wbB, 1)
      G2STEP(7, wbB, wbA, 0)
    }
    #pragma unroll
    for (int it = 0; it < 3; ++it) {
      const int t = it * 4 + wn;
      if (t < 9) {
        if (t < 5) {
          #pragma unroll
          for (int rt = 0; rt < 8; ++rt) {
            const int kgl = k0r + rt * 16 + lj;
            __hip_bfloat16* sp = sct + ((size_t)bq * 80 + t * 16 + lr4) * 512 + kgl;
            #pragma unroll
            for (int rr = 0; rr < 4; ++rr) sp[rr * 512] = __float2bfloat16(a2[it][rt][rr]);
          }
        } else {
          #pragma unroll
          for (int rt = 0; rt < 8; ++rt) {
            const int kgl = k0r + rt * 16 + lj;
            float4 v; v.x = a2[it][rt][0]; v.y = a2[it][rt][1]; v.z = a2[it][rt][2]; v.w = a2[it][rt][3];
            *(float4*)&edge_out[((size_t)bq * 512 + kgl) * 64 + (t * 16 - 80) + lr4] = v;
          }
        }
      }
    }
  }
#undef LOADW1
#undef G1STEP
#undef LOADW2
#undef G2STEP
}

// ===================== attention + outputs (coalesced, no-max softmax) =====================
__global__ __launch_bounds__(512) void attn_kernel(
    const __hip_bfloat16* __restrict__ sct, const int* __restrict__ adj,
    const float* __restrict__ projt, const float* __restrict__ pft,
    const float* __restrict__ eow, const float* __restrict__ iow,
    const float* __restrict__ iob, float* __restrict__ out) {
  __shared__ float eo_s[3][64];
  __shared__ float io_s[256];

  const int bq = blockIdx.x, b = bq >> 8;
  const int tid = threadIdx.x, lane = tid & 63, w = tid >> 6;
  const int kb = lane * 8;

  const int4 aj0 = *(const int4*)&adj[(size_t)bq * 512 + kb];
  const int4 aj1 = *(const int4*)&adj[(size_t)bq * 512 + kb + 4];
  const unsigned int mk = (aj0.x > 0 ? 1u : 0) | (aj0.y > 0 ? 2u : 0) | (aj0.z > 0 ? 4u : 0) | (aj0.w > 0 ? 8u : 0)
                        | (aj1.x > 0 ? 16u : 0) | (aj1.y > 0 ? 32u : 0) | (aj1.z > 0 ? 64u : 0) | (aj1.w > 0 ? 128u : 0);

  // ---- Phase A: equi channels d = w*8 .. w*8+7 ----
  for (int dd = 0; dd < 8; ++dd) {
    const int d = w * 8 + dd;
    const bf16x8 s8 = *(const bf16x8*)&sct[((size_t)bq * 80 + d) * 512 + kb];
    float p[8], z = 0.f, s2 = 0.f;
    #pragma unroll
    for (int j = 0; j < 8; ++j) {
      const float e = ((mk >> j) & 1) ? __expf(b2f((unsigned short)s8[j])) : 0.f;
      p[j] = e; z += e; s2 += e * e;
    }
    float ax[3];
    #pragma unroll
    for (int x = 0; x < 3; ++x) {
      const float* pr = projt + ((size_t)(b * 3 + x) * 64 + d) * 512 + kb;
      const float4 w0 = *(const float4*)pr;
      const float4 w1v = *(const float4*)(pr + 4);
      ax[x] = p[0] * w0.x + p[1] * w0.y + p[2] * w0.z + p[3] * w0.w
            + p[4] * w1v.x + p[5] * w1v.y + p[6] * w1v.z + p[7] * w1v.w;
    }
    #pragma unroll
    for (int off = 32; off; off >>= 1) {
      z += __shfl_xor(z, off, 64); s2 += __shfl_xor(s2, off, 64);
      ax[0] += __shfl_xor(ax[0], off, 64); ax[1] += __shfl_xor(ax[1], off, 64); ax[2] += __shfl_xor(ax[2], off, 64);
    }
    if (lane == 0) {
      const float sc = sqrtf(s2) / (z * z);
      eo_s[0][d] = ax[0] * sc; eo_s[1][d] = ax[1] * sc; eo_s[2][d] = ax[2] * sc;
    }
  }

  // ---- Phase B: inv heads h = w*2 .. w*2+1 ----
  #pragma unroll
  for (int hh = 0; hh < 2; ++hh) {
    const int h = w * 2 + hh;
    const bf16x8 s8 = *(const bf16x8*)&sct[((size_t)bq * 80 + 64 + h) * 512 + kb];
    float p[8], z = 0.f, s2 = 0.f;
    #pragma unroll
    for (int j = 0; j < 8; ++j) {
      const float e = ((mk >> j) & 1) ? __expf(b2f((unsigned short)s8[j])) : 0.f;
      p[j] = e; z += e; s2 += e * e;
    }
    f32x4 io[4];
    #pragma unroll
    for (int d4 = 0; d4 < 4; ++d4)
      #pragma unroll
      for (int di = 0; di < 4; ++di) {
        const float* pr = pft + ((size_t)(b * 256) + h * 16 + d4 * 4 + di) * 512 + kb;
        const float4 w0 = *(const float4*)pr;
        const float4 w1v = *(const float4*)(pr + 4);
        io[d4][di] = p[0] * w0.x + p[1] * w0.y + p[2] * w0.z + p[3] * w0.w
                   + p[4] * w1v.x + p[5] * w1v.y + p[6] * w1v.z + p[7] * w1v.w;
      }
    #pragma unroll
    for (int off = 32; off; off >>= 1) {
      z += __shfl_xor(z, off, 64); s2 += __shfl_xor(s2, off, 64);
      #pragma unroll
      for (int d4 = 0; d4 < 4; ++d4)
        #pragma unroll
        for (int di = 0; di < 4; ++di)
          io[d4][di] += __shfl_xor(io[d4][di], off, 64);
    }
    if (lane == 0) {
      const float sc = sqrtf(s2) / (z * z);
      #pragma unroll
      for (int d4 = 0; d4 < 4; ++d4) {
        float4 vv; vv.x = io[d4][0] * sc; vv.y = io[d4][1] * sc; vv.z = io[d4][2] * sc; vv.w = io[d4][3] * sc;
        *(float4*)&io_s[h * 16 + d4 * 4] = vv;
      }
    }
  }
  __syncthreads();

  if (tid < 192) {   // equi_out = eo @ equi_out_w
    const int x = tid >> 6, e = tid & 63;
    float a = 0.f;
    for (int d = 0; d < 64; ++d) a += eo_s[x][d] * eow[(size_t)d * 64 + e];
    out[(size_t)bq * 192 + x * 64 + e] = a;
  }
  if (tid < 256) {   // inv_out = io @ inv_out_w + iob
    float a = iob[tid];
    for (int k = 0; k < 256; ++k) a += io_s[k] * iow[(size_t)k * 256 + tid];
    out[98304 + (size_t)bq * 256 + tid] = a;
  }
}

// ===================== launch =====================
extern "C" void kernel_launch(void* const* d_in, const int* in_sizes, int n_in,
                              void* d_out, int out_size, void* d_ws, size_t ws_size,
                              hipStream_t stream) {
  const float* equis      = (const float*)d_in[0];
  const float* invs       = (const float*)d_in[1];
  const float* cond_equis = (const float*)d_in[2];
  const float* cond_invs  = (const float*)d_in[3];
  const float* edges      = (const float*)d_in[4];
  const int*   adj        = (const int*)d_in[5];
  const float* q_w  = (const float*)d_in[6];
  const float* q_b  = (const float*)d_in[7];
  const float* k_w  = (const float*)d_in[8];
  const float* k_b  = (const float*)d_in[9];
  const float* w1   = (const float*)d_in[10];
  const float* b1   = (const float*)d_in[11];
  const float* w2   = (const float*)d_in[12];
  const float* b2   = (const float*)d_in[13];
  const float* equi_in_w  = (const float*)d_in[14];
  const float* equi_out_w = (const float*)d_in[15];
  const float* inv_in_w   = (const float*)d_in[16];
  const float* inv_in_b   = (const float*)d_in[17];
  const float* inv_out_w  = (const float*)d_in[18];
  const float* inv_out_b  = (const float*)d_in[19];

  float* out = (float*)d_out;
  float* ws  = (float*)d_ws;
  unsigned short* w1t = (unsigned short*)ws;             // 65536 us
  unsigned short* w2t = w1t + 65536;                     // 36864 us  (-> 51200 floats)
  float* qm    = ws + 51200;                             // 32768
  float* km    = qm + 32768;                             // 65536
  float* projt = km + 65536;                             // 196608  [b][x][d][512]
  float* pft   = projt + 196608;                         // 262144  [b][ch][512]
  __hip_bfloat16* sct = (__hip_bfloat16*)(pft + 262144); // 512*80*512 bf16 = 41.9 MB

  prep_w_kernel<<<400, 256, 0, stream>>>(w1, w2, w1t, w2t);
  qk_kernel<<<1536, 64, 0, stream>>>(invs, cond_invs, q_w, q_b, k_w, k_b, qm, km);
  projt_kernel<<<3072, 64, 0, stream>>>(cond_equis, equi_in_w, projt);
  pft_kernel<<<1024, 256, 0, stream>>>(cond_invs, inv_in_w, inv_in_b, pft);

  msg_kernel<<<2048, 256, 0, stream>>>(equis, cond_equis, edges, qm, km,
                                       w1t, b1, w2t, b2,
                                       out + 229376 /*edge_out*/, sct);

  attn_kernel<<<512, 512, 0, stream>>>(sct, adj, projt, pft,
                                       equi_out_w, inv_out_w, inv_out_b, out);
}

// Round 6
// 177.331 us; speedup vs baseline: 7.5615x; 1.0855x over previous
//
#include <hip/hip_runtime.h>
#include <hip/hip_bf16.h>

#define DEVINL static __device__ __forceinline__

typedef __attribute__((ext_vector_type(8))) short bf16x8;
typedef __attribute__((ext_vector_type(8))) unsigned short us8;
typedef __attribute__((ext_vector_type(4))) float f32x4;
typedef __attribute__((ext_vector_type(4))) unsigned short us4;

DEVINL float siluf(float x) { return x / (1.0f + __expf(-x)); }
DEVINL unsigned short bfb(float x) { __hip_bfloat16 h = __float2bfloat16(x); return *(unsigned short*)&h; }
DEVINL float b2f(unsigned short u) { return __uint_as_float(((unsigned int)u) << 16); }

// ===================== prep: weights in FRAGMENT ORDER (coalesced loads in msg) =====================
// w1f[g][kk][lane][e] = bf16(w1[k][c]) with c = g*16 + (lane&15), k = kk*32 + (lane>>4)*8 + e
// blocks 0..15 -> w1 groups; 16..24 -> w2 groups
__global__ void wfrag_kernel(const float* __restrict__ w1, const float* __restrict__ w2,
                             unsigned short* __restrict__ w1f, unsigned short* __restrict__ w2f) {
  const int g = blockIdx.x, tid = threadIdx.x;
  if (g < 16) {
    #pragma unroll
    for (int e2 = 0; e2 < 16; ++e2) {
      const int flat = tid * 16 + e2;                 // 0..4095
      const int kk = flat >> 9, rem = flat & 511, ln = rem >> 3, e = rem & 7;
      const int c = g * 16 + (ln & 15);
      const int k = kk * 32 + (ln >> 4) * 8 + e;
      w1f[(size_t)g * 4096 + flat] = bfb(w1[(size_t)k * 256 + c]);
    }
  } else {
    const int t = g - 16;
    #pragma unroll
    for (int e2 = 0; e2 < 16; ++e2) {
      const int flat = tid * 16 + e2;
      const int kk = flat >> 9, rem = flat & 511, ln = rem >> 3, e = rem & 7;
      const int c = t * 16 + (ln & 15);
      const int k = kk * 32 + (ln >> 4) * 8 + e;
      w2f[(size_t)t * 4096 + flat] = bfb(w2[(size_t)k * 144 + c]);
    }
  }
}

// ===================== prep: cond_equis -> bf16 (row-contiguous) =====================
__global__ void cet_kernel(const float* __restrict__ ce, unsigned short* __restrict__ cet) {
  const size_t i = (size_t)blockIdx.x * 192 + threadIdx.x;
  cet[i] = bfb(ce[i]);
}

// ===================== prep: q_msg / k_msg =====================
__global__ void qk_kernel(const float* __restrict__ invs, const float* __restrict__ cond_invs,
                          const float* __restrict__ qw, const float* __restrict__ qb,
                          const float* __restrict__ kw, const float* __restrict__ kb2,
                          float* __restrict__ qm, float* __restrict__ km) {
  __shared__ float srow[256];
  const int r = blockIdx.x;
  const float* in; const float* w; const float* bias; float* out; int row;
  if (r < 512) { in = invs;      w = qw; bias = qb;  out = qm; row = r; }
  else         { in = cond_invs; w = kw; bias = kb2; out = km; row = r - 512; }
  for (int k = threadIdx.x; k < 256; k += 64) srow[k] = in[(size_t)row * 256 + k];
  __syncthreads();
  const int c = threadIdx.x;
  float acc = bias[c];
  for (int k = 0; k < 256; ++k) acc += srow[k] * w[(size_t)k * 64 + c];
  out[(size_t)row * 64 + c] = acc;
}

// ===================== prep: proj transposed k-major =====================
__global__ void projt_kernel(const float* __restrict__ ce, const float* __restrict__ eiw,
                             float* __restrict__ projt) {
  __shared__ float srow[64];
  const int r = blockIdx.x;
  const int b = r / 1536, rr = r % 1536, kn = rr / 3, x = rr % 3;
  srow[threadIdx.x] = ce[(size_t)r * 64 + threadIdx.x];
  __syncthreads();
  const int c = threadIdx.x;
  float acc = 0.f;
  for (int k = 0; k < 64; ++k) acc += srow[k] * eiw[(size_t)k * 64 + c];
  projt[((size_t)(b * 3 + x) * 64 + c) * 512 + kn] = acc;
}

// ===================== prep: pf transposed k-major =====================
__global__ void pft_kernel(const float* __restrict__ ci, const float* __restrict__ iiw,
                           const float* __restrict__ iib, float* __restrict__ pft) {
  __shared__ float srow[256];
  const int r = blockIdx.x, b = r >> 9, kn = r & 511;
  srow[threadIdx.x] = ci[(size_t)r * 256 + threadIdx.x];
  __syncthreads();
  const int c = threadIdx.x;
  float acc = iib[c];
  for (int k = 0; k < 256; ++k) acc += srow[k] * iiw[(size_t)k * 256 + c];
  pft[((size_t)(b * 256) + c) * 512 + kn] = acc;
}

// ===================== main message kernel (all accesses coalesced) =====================
// grid = 512 (b,q) x 8 k-tiles of 64 rows; block = 256 threads (4 waves)
__global__ __launch_bounds__(256, 2) void msg_kernel(
    const float* __restrict__ equis, const float* __restrict__ edges,
    const float* __restrict__ qm, const float* __restrict__ km,
    const unsigned short* __restrict__ cet,
    const unsigned short* __restrict__ w1f, const float* __restrict__ b1,
    const unsigned short* __restrict__ w2f, const float* __restrict__ b2,
    float* __restrict__ edge_out, __hip_bfloat16* __restrict__ sct) {
  // LDS: [0,25600) tile[64][200] (feats cols 0..191) / later score_s[64][88]
  //      [25600,59392) hbuf[64][264] (h)  / earlier ce_s[64][200] / later edge_s[64][68]
  __shared__ __align__(16) unsigned char smem[59392];
  unsigned short (*tile)[200]   = (unsigned short (*)[200])smem;
  unsigned short (*hbuf)[264]   = (unsigned short (*)[264])(smem + 25600);
  unsigned short (*ce_s)[200]   = (unsigned short (*)[200])(smem + 25600);
  unsigned short (*score_s)[88] = (unsigned short (*)[88])smem;
  float (*edge_s)[68]           = (float (*)[68])(smem + 25600);

  const int bq = blockIdx.x >> 3;     // b*256+q
  const int b  = bq >> 8;
  const int k0 = (blockIdx.x & 7) * 64;
  const int tid = threadIdx.x;
  const int lane = tid & 63, wn = tid >> 6;
  const int lj  = lane & 15;
  const int lkb = (lane >> 4) * 8;
  const int lr4 = (lane >> 4) * 4;

  // ---- qm fragments (k rows 0..63 of w1; row-invariant over output rows) ----
  bf16x8 qf[2];
  {
    const float* qmr = qm + (size_t)bq * 64;
    #pragma unroll
    for (int kk = 0; kk < 2; ++kk) {
      const float4 a = *(const float4*)&qmr[kk * 32 + (lane >> 4) * 8];
      const float4 c = *(const float4*)&qmr[kk * 32 + (lane >> 4) * 8 + 4];
      bf16x8 v;
      v[0] = (short)bfb(a.x); v[1] = (short)bfb(a.y); v[2] = (short)bfb(a.z); v[3] = (short)bfb(a.w);
      v[4] = (short)bfb(c.x); v[5] = (short)bfb(c.y); v[6] = (short)bfb(c.z); v[7] = (short)bfb(c.w);
      qf[kk] = v;
    }
  }

  // ---- stage km (tile cols 0..63), edges (cols 128..191), cet raw (ce_s) — all coalesced ----
  #pragma unroll
  for (int it = 0; it < 4; ++it) {
    const int flat = it * 256 + tid, row = flat >> 4, seg = flat & 15;
    const float4 v = *(const float4*)&km[((size_t)(b * 512 + k0 + row)) * 64 + seg * 4];
    us4 u = { bfb(v.x), bfb(v.y), bfb(v.z), bfb(v.w) };
    *(us4*)&tile[row][seg * 4] = u;
  }
  #pragma unroll
  for (int it = 0; it < 4; ++it) {
    const int flat = it * 256 + tid, row = flat >> 4, seg = flat & 15;
    const float4 v = *(const float4*)&edges[((size_t)bq * 512 + k0 + row) * 64 + seg * 4];
    us4 u = { bfb(v.x), bfb(v.y), bfb(v.z), bfb(v.w) };
    *(us4*)&tile[row][128 + seg * 4] = u;
  }
  #pragma unroll
  for (int it = 0; it < 6; ++it) {
    const int flat = it * 256 + tid, row = flat / 24, seg = flat % 24;
    const us8 v = *(const us8*)&cet[((size_t)(b * 512 + k0 + row)) * 192 + seg * 8];
    *(us8*)&ce_s[row][seg * 8] = v;
  }
  __syncthreads();

  // ---- dot (tile cols 64..127) from LDS ----
  {
    const int dd = tid & 63, rg = tid >> 6;
    const float e0 = equis[(size_t)bq * 192 + dd];
    const float e1 = equis[(size_t)bq * 192 + 64 + dd];
    const float e2 = equis[(size_t)bq * 192 + 128 + dd];
    #pragma unroll
    for (int it = 0; it < 16; ++it) {
      const int r = it * 4 + rg;
      const float v = e0 * b2f(ce_s[r][dd]) + e1 * b2f(ce_s[r][64 + dd]) + e2 * b2f(ce_s[r][128 + dd]);
      tile[r][64 + dd] = bfb(v);
    }
  }
  __syncthreads();

// ---- coalesced weight-fragment loads ----
#define LW1(BUF, KK) { \
    _Pragma("unroll") for (int ct = 0; ct < 4; ++ct) \
      BUF[ct] = *(const bf16x8*)&w1f[((size_t)(((wn * 4 + ct) * 8 + (KK)) * 64) + lane) * 8]; }

#define G1STEP(KK, CUR, NXT, DOPF) { \
    if (DOPF) { LW1(NXT, (KK) + 1); } \
    if ((KK) < 2) { \
      _Pragma("unroll") for (int ct = 0; ct < 4; ++ct) \
        _Pragma("unroll") for (int rt = 0; rt < 4; ++rt) \
          acc[ct][rt] = __builtin_amdgcn_mfma_f32_16x16x32_bf16(CUR[ct], qf[KK], acc[ct][rt], 0, 0, 0); \
    } else { \
      bf16x8 fbv[4]; \
      _Pragma("unroll") for (int rt = 0; rt < 4; ++rt) \
        fbv[rt] = *(const bf16x8*)&tile[rt * 16 + lj][((KK) - 2) * 32 + lkb]; \
      _Pragma("unroll") for (int ct = 0; ct < 4; ++ct) \
        _Pragma("unroll") for (int rt = 0; rt < 4; ++rt) \
          acc[ct][rt] = __builtin_amdgcn_mfma_f32_16x16x32_bf16(CUR[ct], fbv[rt], acc[ct][rt], 0, 0, 0); \
    } }

  // ---- GEMM1: D1[c][r], c in [wn*64,+64), r in [0,64) ----
  f32x4 acc[4][4];
  #pragma unroll
  for (int ct = 0; ct < 4; ++ct) {
    const float4 bb = *(const float4*)&b1[wn * 64 + ct * 16 + lr4];
    #pragma unroll
    for (int rt = 0; rt < 4; ++rt) { acc[ct][rt][0] = bb.x; acc[ct][rt][1] = bb.y; acc[ct][rt][2] = bb.z; acc[ct][rt][3] = bb.w; }
  }
  {
    bf16x8 waA[4], waB[4];
    LW1(waA, 0);
    G1STEP(0, waA, waB, 1)
    G1STEP(1, waB, waA, 1)
    G1STEP(2, waA, waB, 1)
    G1STEP(3, waB, waA, 1)
    G1STEP(4, waA, waB, 1)
    G1STEP(5, waB, waA, 1)
    G1STEP(6, waA, waB, 1)
    G1STEP(7, waB, waA, 0)
  }

  // ---- h = silu(acc) -> hbuf (no barrier needed: hbuf distinct from tile; ce_s dead) ----
  #pragma unroll
  for (int ct = 0; ct < 4; ++ct)
    #pragma unroll
    for (int rt = 0; rt < 4; ++rt) {
      us4 u = { bfb(siluf(acc[ct][rt][0])), bfb(siluf(acc[ct][rt][1])),
                bfb(siluf(acc[ct][rt][2])), bfb(siluf(acc[ct][rt][3])) };
      *(us4*)&hbuf[rt * 16 + lj][wn * 64 + ct * 16 + lr4] = u;
    }
  __syncthreads();

#define LW2(BUF, KK) { \
    _Pragma("unroll") for (int it = 0; it < 3; ++it) { \
      const int t = it * 4 + wn; \
      if (t < 9) BUF[it] = *(const bf16x8*)&w2f[((size_t)((t * 8 + (KK)) * 64) + lane) * 8]; } }

#define G2STEP(KK, CUR, NXT, DOPF) { \
    if (DOPF) { LW2(NXT, (KK) + 1); } \
    bf16x8 fbv[4]; \
    _Pragma("unroll") for (int rt = 0; rt < 4; ++rt) \
      fbv[rt] = *(const bf16x8*)&hbuf[rt * 16 + lj][(KK) * 32 + lkb]; \
    _Pragma("unroll") for (int it = 0; it < 3; ++it) { \
      const int t = it * 4 + wn; \
      if (t < 9) { \
        _Pragma("unroll") for (int rt = 0; rt < 4; ++rt) \
          a2[it][rt] = __builtin_amdgcn_mfma_f32_16x16x32_bf16(CUR[it], fbv[rt], a2[it][rt], 0, 0, 0); \
      } } }

  // ---- GEMM2: 9 channel-tiles, t = it*4 + wn ----
  f32x4 a2[3][4];
  #pragma unroll
  for (int it = 0; it < 3; ++it) {
    const int t = it * 4 + wn;
    if (t < 9) {
      const float4 bb = *(const float4*)&b2[t * 16 + lr4];
      #pragma unroll
      for (int rt = 0; rt < 4; ++rt) { a2[it][rt][0] = bb.x; a2[it][rt][1] = bb.y; a2[it][rt][2] = bb.z; a2[it][rt][3] = bb.w; }
    }
  }
  {
    bf16x8 wbA[3], wbB[3];
    LW2(wbA, 0);
    G2STEP(0, wbA, wbB, 1)
    G2STEP(1, wbB, wbA, 1)
    G2STEP(2, wbA, wbB, 1)
    G2STEP(3, wbB, wbA, 1)
    G2STEP(4, wbA, wbB, 1)
    G2STEP(5, wbB, wbA, 1)
    G2STEP(6, wbA, wbB, 1)
    G2STEP(7, wbB, wbA, 0)
  }
  __syncthreads();   // all reads of tile/hbuf done -> safe to overwrite with bounce buffers

  // ---- bounce accumulators to LDS (score_s over tile area, edge_s over hbuf area) ----
  #pragma unroll
  for (int it = 0; it < 3; ++it) {
    const int t = it * 4 + wn;
    if (t < 9) {
      if (t < 5) {
        #pragma unroll
        for (int rt = 0; rt < 4; ++rt) {
          us4 u = { bfb(a2[it][rt][0]), bfb(a2[it][rt][1]), bfb(a2[it][rt][2]), bfb(a2[it][rt][3]) };
          *(us4*)&score_s[rt * 16 + lj][t * 16 + lr4] = u;
        }
      } else {
        #pragma unroll
        for (int rt = 0; rt < 4; ++rt) {
          float4 v; v.x = a2[it][rt][0]; v.y = a2[it][rt][1]; v.z = a2[it][rt][2]; v.w = a2[it][rt][3];
          *(float4*)&edge_s[rt * 16 + lj][(t - 5) * 16 + lr4] = v;
        }
      }
    }
  }
  __syncthreads();

  // ---- coalesced global stores ----
  // scores: 80 ch x 8 k-segments (16B each)
  #pragma unroll
  for (int it = 0; it < 3; ++it) {
    const int idx = it * 256 + tid;
    if (idx < 640) {
      const int c = idx >> 3, s = idx & 7;
      bf16x8 v;
      #pragma unroll
      for (int j = 0; j < 8; ++j) v[j] = (short)score_s[s * 8 + j][c];
      *(bf16x8*)&sct[((size_t)bq * 80 + c) * 512 + k0 + s * 8] = v;
    }
  }
  // edges: 64 rows x 16 float4 segments
  #pragma unroll
  for (int it = 0; it < 4; ++it) {
    const int idx = it * 256 + tid;
    const int row = idx >> 4, sg = idx & 15;
    *(float4*)&edge_out[((size_t)bq * 512 + k0 + row) * 64 + sg * 4] = *(const float4*)&edge_s[row][sg * 4];
  }
#undef LW1
#undef G1STEP
#undef LW2
#undef G2STEP
}

// ===================== attention + outputs (coalesced, no-max softmax) =====================
__global__ __launch_bounds__(512) void attn_kernel(
    const __hip_bfloat16* __restrict__ sct, const int* __restrict__ adj,
    const float* __restrict__ projt, const float* __restrict__ pft,
    const float* __restrict__ eow, const float* __restrict__ iow,
    const float* __restrict__ iob, float* __restrict__ out) {
  __shared__ float eo_s[3][64];
  __shared__ float io_s[256];

  const int bq = blockIdx.x, b = bq >> 8;
  const int tid = threadIdx.x, lane = tid & 63, w = tid >> 6;
  const int kb = lane * 8;

  const int4 aj0 = *(const int4*)&adj[(size_t)bq * 512 + kb];
  const int4 aj1 = *(const int4*)&adj[(size_t)bq * 512 + kb + 4];
  const unsigned int mk = (aj0.x > 0 ? 1u : 0) | (aj0.y > 0 ? 2u : 0) | (aj0.z > 0 ? 4u : 0) | (aj0.w > 0 ? 8u : 0)
                        | (aj1.x > 0 ? 16u : 0) | (aj1.y > 0 ? 32u : 0) | (aj1.z > 0 ? 64u : 0) | (aj1.w > 0 ? 128u : 0);

  // ---- Phase A: equi channels d = w*8 .. w*8+7 ----
  for (int dd = 0; dd < 8; ++dd) {
    const int d = w * 8 + dd;
    const bf16x8 s8 = *(const bf16x8*)&sct[((size_t)bq * 80 + d) * 512 + kb];
    float p[8], z = 0.f, s2 = 0.f;
    #pragma unroll
    for (int j = 0; j < 8; ++j) {
      const float e = ((mk >> j) & 1) ? __expf(b2f((unsigned short)s8[j])) : 0.f;
      p[j] = e; z += e; s2 += e * e;
    }
    float ax[3];
    #pragma unroll
    for (int x = 0; x < 3; ++x) {
      const float* pr = projt + ((size_t)(b * 3 + x) * 64 + d) * 512 + kb;
      const float4 w0 = *(const float4*)pr;
      const float4 w1v = *(const float4*)(pr + 4);
      ax[x] = p[0] * w0.x + p[1] * w0.y + p[2] * w0.z + p[3] * w0.w
            + p[4] * w1v.x + p[5] * w1v.y + p[6] * w1v.z + p[7] * w1v.w;
    }
    #pragma unroll
    for (int off = 32; off; off >>= 1) {
      z += __shfl_xor(z, off, 64); s2 += __shfl_xor(s2, off, 64);
      ax[0] += __shfl_xor(ax[0], off, 64); ax[1] += __shfl_xor(ax[1], off, 64); ax[2] += __shfl_xor(ax[2], off, 64);
    }
    if (lane == 0) {
      const float sc = sqrtf(s2) / (z * z);
      eo_s[0][d] = ax[0] * sc; eo_s[1][d] = ax[1] * sc; eo_s[2][d] = ax[2] * sc;
    }
  }

  // ---- Phase B: inv heads h = w*2 .. w*2+1 ----
  #pragma unroll
  for (int hh = 0; hh < 2; ++hh) {
    const int h = w * 2 + hh;
    const bf16x8 s8 = *(const bf16x8*)&sct[((size_t)bq * 80 + 64 + h) * 512 + kb];
    float p[8], z = 0.f, s2 = 0.f;
    #pragma unroll
    for (int j = 0; j < 8; ++j) {
      const float e = ((mk >> j) & 1) ? __expf(b2f((unsigned short)s8[j])) : 0.f;
      p[j] = e; z += e; s2 += e * e;
    }
    f32x4 io[4];
    #pragma unroll
    for (int d4 = 0; d4 < 4; ++d4)
      #pragma unroll
      for (int di = 0; di < 4; ++di) {
        const float* pr = pft + ((size_t)(b * 256) + h * 16 + d4 * 4 + di) * 512 + kb;
        const float4 w0 = *(const float4*)pr;
        const float4 w1v = *(const float4*)(pr + 4);
        io[d4][di] = p[0] * w0.x + p[1] * w0.y + p[2] * w0.z + p[3] * w0.w
                   + p[4] * w1v.x + p[5] * w1v.y + p[6] * w1v.z + p[7] * w1v.w;
      }
    #pragma unroll
    for (int off = 32; off; off >>= 1) {
      z += __shfl_xor(z, off, 64); s2 += __shfl_xor(s2, off, 64);
      #pragma unroll
      for (int d4 = 0; d4 < 4; ++d4)
        #pragma unroll
        for (int di = 0; di < 4; ++di)
          io[d4][di] += __shfl_xor(io[d4][di], off, 64);
    }
    if (lane == 0) {
      const float sc = sqrtf(s2) / (z * z);
      #pragma unroll
      for (int d4 = 0; d4 < 4; ++d4) {
        float4 vv; vv.x = io[d4][0] * sc; vv.y = io[d4][1] * sc; vv.z = io[d4][2] * sc; vv.w = io[d4][3] * sc;
        *(float4*)&io_s[h * 16 + d4 * 4] = vv;
      }
    }
  }
  __syncthreads();

  if (tid < 192) {   // equi_out = eo @ equi_out_w
    const int x = tid >> 6, e = tid & 63;
    float a = 0.f;
    for (int d = 0; d < 64; ++d) a += eo_s[x][d] * eow[(size_t)d * 64 + e];
    out[(size_t)bq * 192 + x * 64 + e] = a;
  }
  if (tid < 256) {   // inv_out = io @ inv_out_w + iob
    float a = iob[tid];
    for (int k = 0; k < 256; ++k) a += io_s[k] * iow[(size_t)k * 256 + tid];
    out[98304 + (size_t)bq * 256 + tid] = a;
  }
}

// ===================== launch =====================
extern "C" void kernel_launch(void* const* d_in, const int* in_sizes, int n_in,
                              void* d_out, int out_size, void* d_ws, size_t ws_size,
                              hipStream_t stream) {
  const float* equis      = (const float*)d_in[0];
  const float* invs       = (const float*)d_in[1];
  const float* cond_equis = (const float*)d_in[2];
  const float* cond_invs  = (const float*)d_in[3];
  const float* edges      = (const float*)d_in[4];
  const int*   adj        = (const int*)d_in[5];
  const float* q_w  = (const float*)d_in[6];
  const float* q_b  = (const float*)d_in[7];
  const float* k_w  = (const float*)d_in[8];
  const float* k_b  = (const float*)d_in[9];
  const float* w1   = (const float*)d_in[10];
  const float* b1   = (const float*)d_in[11];
  const float* w2   = (const float*)d_in[12];
  const float* b2   = (const float*)d_in[13];
  const float* equi_in_w  = (const float*)d_in[14];
  const float* equi_out_w = (const float*)d_in[15];
  const float* inv_in_w   = (const float*)d_in[16];
  const float* inv_in_b   = (const float*)d_in[17];
  const float* inv_out_w  = (const float*)d_in[18];
  const float* inv_out_b  = (const float*)d_in[19];

  float* out = (float*)d_out;
  float* ws  = (float*)d_ws;
  unsigned short* w1f = (unsigned short*)ws;             // 65536 us
  unsigned short* w2f = w1f + 65536;                     // 36864 us  (-> 51200 floats total)
  float* qm    = ws + 51200;                             // 32768 f
  float* km    = qm + 32768;                             // 65536 f
  float* projt = km + 65536;                             // 196608 f [b][x][d][512]
  float* pft   = projt + 196608;                         // 262144 f [b][ch][512]
  unsigned short* cet = (unsigned short*)(pft + 262144); // 196608 us [b][k][192]
  __hip_bfloat16* sct = (__hip_bfloat16*)(pft + 262144 + 98304); // 512*80*512 bf16

  wfrag_kernel<<<25, 256, 0, stream>>>(w1, w2, w1f, w2f);
  cet_kernel<<<1024, 192, 0, stream>>>(cond_equis, cet);
  qk_kernel<<<1536, 64, 0, stream>>>(invs, cond_invs, q_w, q_b, k_w, k_b, qm, km);
  projt_kernel<<<3072, 64, 0, stream>>>(cond_equis, equi_in_w, projt);
  pft_kernel<<<1024, 256, 0, stream>>>(cond_invs, inv_in_w, inv_in_b, pft);

  msg_kernel<<<4096, 256, 0, stream>>>(equis, edges, qm, km, cet,
                                       w1f, b1, w2f, b2,
                                       out + 229376 /*edge_out*/, sct);

  attn_kernel<<<512, 512, 0, stream>>>(sct, adj, projt, pft,
                                       equi_out_w, inv_out_w, inv_out_b, out);
}